// Round 22
// baseline (328.026 us; speedup 1.0000x reference)
//
#include <hip/hip_runtime.h>
#include <hip/hip_fp16.h>
#include <math.h>

#define F1 128
#define C2N 8
#define SLOPE 0.2f
#define EPSBN 1e-5f
#define BCAP 4096
#define SB 4096
#define BSH 7      // 128 nodes per bucket
#define MAXB 1024

typedef float floatx2 __attribute__((ext_vector_type(2)));

__device__ __forceinline__ unsigned fenc(float f){
  unsigned u = __float_as_uint(f);
  return (u & 0x80000000u) ? ~u : (u | 0x80000000u);
}
__device__ __forceinline__ float fdec(unsigned u){
  return (u & 0x80000000u) ? __uint_as_float(u & 0x7FFFFFFFu) : __uint_as_float(~u);
}
__device__ __forceinline__ float2 h2f2(unsigned u){
  __half2 h = *(__half2*)&u;
  return __half22float2(h);
}

// ---- fused: BatchNorm stats (blocks 0..255) || dst-degree histogram (rest) ----
__global__ __launch_bounds__(256) void k_bn_deg(const float* __restrict__ x,
    float* __restrict__ sum, float* __restrict__ sumsq, int n,
    const int* __restrict__ ei, int* __restrict__ deg, int E){
  if ((int)blockIdx.x >= 256){
    int e = ((int)blockIdx.x - 256)*256 + threadIdx.x;
    if (e < E) atomicAdd(&deg[ei[E + e]], 1);
    return;
  }
  int t  = threadIdx.x;
  int c4 = (t & 31) * 4;
  int rg = t >> 5;
  float4 s = {0,0,0,0}, q = {0,0,0,0};
  for (int r = blockIdx.x*8 + rg; r < n; r += 2048){
    float4 v = *(const float4*)&x[(size_t)r*F1 + c4];
    s.x += v.x; s.y += v.y; s.z += v.z; s.w += v.w;
    q.x += v.x*v.x; q.y += v.y*v.y; q.z += v.z*v.z; q.w += v.w*v.w;
  }
  s.x += __shfl_xor(s.x, 32); s.y += __shfl_xor(s.y, 32);
  s.z += __shfl_xor(s.z, 32); s.w += __shfl_xor(s.w, 32);
  q.x += __shfl_xor(q.x, 32); q.y += __shfl_xor(q.y, 32);
  q.z += __shfl_xor(q.z, 32); q.w += __shfl_xor(q.w, 32);
  __shared__ float red[2][4][F1];
  int w = t >> 6;
  int l = t & 63;
  if (l < 32){
    *(float4*)&red[0][w][l*4] = s;
    *(float4*)&red[1][w][l*4] = q;
  }
  __syncthreads();
  if (t < 128){
    float a = red[0][0][t] + red[0][1][t] + red[0][2][t] + red[0][3][t];
    atomicAdd(&sum[t], a);
  } else {
    int f = t - 128;
    float a = red[1][0][f] + red[1][1][f] + red[1][2][f] + red[1][3][f];
    atomicAdd(&sumsq[f], a);
  }
}

// ---- fused: scan A (blocks 0..nb-1) || bn_final (last block) ----
__global__ __launch_bounds__(256) void k_scan_a_bn(const int* __restrict__ deg,
    int* __restrict__ rowptr, int* __restrict__ bsum, int n,
    const float* __restrict__ sum, const float* __restrict__ sumsq,
    const float* __restrict__ gamma, const float* __restrict__ beta,
    float* __restrict__ ab){
  int nbS = gridDim.x - 1;
  if ((int)blockIdx.x == nbS){
    int f = threadIdx.x;
    if (f < 128){
      float inv_n = 1.f / (float)n;
      float mean = sum[f] * inv_n;
      float var  = sumsq[f] * inv_n - mean*mean;
      float inv  = rsqrtf(var + EPSBN);
      float a = inv * gamma[f];
      ab[f]      = a;
      ab[F1 + f] = beta[f] - mean*a;
    }
    return;
  }
  int t = threadIdx.x;
  int base = blockIdx.x*1024 + t*4;
  int4 v = {0,0,0,0};
  if (base + 3 < n){
    v = *(const int4*)&deg[base];
    v.x += 1; v.y += 1; v.z += 1; v.w += 1;
  } else {
    if (base   < n) v.x = deg[base]   + 1;
    if (base+1 < n) v.y = deg[base+1] + 1;
    if (base+2 < n) v.z = deg[base+2] + 1;
    if (base+3 < n) v.w = deg[base+3] + 1;
  }
  int s = v.x + v.y + v.z + v.w;
  __shared__ int ls[256];
  ls[t] = s; __syncthreads();
  for (int off = 1; off < 256; off <<= 1){
    int u = (t >= off) ? ls[t-off] : 0;
    __syncthreads();
    ls[t] += u;
    __syncthreads();
  }
  int ex = ls[t] - s;
  if (t == 255) bsum[blockIdx.x] = ls[255];
  int4 w;
  w.x = ex;
  w.y = ex + v.x;
  w.z = w.y + v.y;
  w.w = w.z + v.z;
  if (base + 3 < n) *(int4*)&rowptr[base] = w;
  else {
    if (base   < n) rowptr[base]   = w.x;
    if (base+1 < n) rowptr[base+1] = w.y;
    if (base+2 < n) rowptr[base+2] = w.z;
    if (base+3 < n) rowptr[base+3] = w.w;
  }
}

// ---- fused: normalize + x@W1 + al1/ar1 (blocks < nbG) || scan C (rest) ----
__global__ __launch_bounds__(256) void k_gemm1_scanc(const float* __restrict__ x,
    const float* __restrict__ ab, const float* __restrict__ W1,
    const float* __restrict__ asrc, const float* __restrict__ adst,
    unsigned char* __restrict__ h1, float* __restrict__ al, float* __restrict__ ar,
    int n, int* __restrict__ rowptr, int* __restrict__ cursor,
    const int* __restrict__ bsum, int nb, int nbG){
  if ((int)blockIdx.x >= nbG){
    int sb = (int)blockIdx.x - nbG;      // scan-C block id, 0..nb-1
    int t = threadIdx.x;
    __shared__ int s_boff;
    if (t < 64){
      int val = 0;
      for (int i = t; i < sb; i += 64) val += bsum[i];
      #pragma unroll
      for (int m = 1; m < 64; m <<= 1) val += __shfl_xor(val, m);
      if (t == 0) s_boff = val;
    }
    __syncthreads();
    int boff = s_boff;
    if (t == 0 && sb == nb - 1)
      rowptr[n] = boff + bsum[sb];
    int base = sb*1024 + t*4;
    if (base + 3 < n){
      int4 v = *(int4*)&rowptr[base];
      v.x += boff; v.y += boff; v.z += boff; v.w += boff;
      *(int4*)&rowptr[base] = v;
      *(int4*)&cursor[base] = v;
    } else {
      for (int k = 0; k < 4; ++k)
        if (base + k < n){
          int v = rowptr[base+k] + boff;
          rowptr[base+k] = v; cursor[base+k] = v;
        }
    }
    return;
  }
  const int j    = threadIdx.x & 127;
  const int half = threadIdx.x >> 7;
  const int r0   = blockIdx.x * 16 + half*8;
  __shared__ float xs[16][F1];
  float A = ab[j], B = ab[F1 + j];
  int nr = n - r0; if (nr > 8) nr = 8; if (nr < 0) nr = 0;
  for (int rr = 0; rr < nr; ++rr)
    xs[half*8+rr][j] = x[(size_t)(r0+rr)*F1 + j] * A + B;
  __syncthreads();
  float acc[8] = {0,0,0,0,0,0,0,0};
  for (int k = 0; k < F1; ++k){
    float w = W1[k*F1 + j];
    #pragma unroll
    for (int rr = 0; rr < 8; ++rr) acc[rr] += xs[half*8+rr][k] * w;
  }
  float as = asrc[j], ad = adst[j];
  for (int rr = 0; rr < nr; ++rr){
    float hv = acc[rr];
    int pk = __builtin_amdgcn_cvt_pk_fp8_f32(hv, hv, 0, false);
    h1[(size_t)(r0+rr)*F1 + j] = (unsigned char)(pk & 0xFF);
    float vs = hv*as, vd = hv*ad;
    #pragma unroll
    for (int mk = 1; mk < 32; mk <<= 1){
      vs += __shfl_xor(vs, mk);
      vd += __shfl_xor(vd, mk);
    }
    if ((j & 31) == 0){
      al[(r0+rr)*4 + (j>>5)] = vs;
      ar[(r0+rr)*4 + (j>>5)] = vd;
    }
  }
}

// ---- global column max (standalone; layer 2) ----
__global__ __launch_bounds__(256) void k_colmax(const float* __restrict__ v,
    unsigned* __restrict__ out, int total, int H){
  int tid = blockIdx.x*256 + threadIdx.x;
  int stride = gridDim.x*256;
  float mx = -1e30f;
  for (int i = tid; i < total; i += stride)
    mx = fmaxf(mx, v[i]);
  for (int m = H; m < 64; m <<= 1)
    mx = fmaxf(mx, __shfl_xor(mx, m));
  int lane = threadIdx.x & 63;
  if (lane < H) atomicMax(&out[lane], fenc(mx));
}

// ---- fused: counting sort (blocks < nbS, relative bcur) || colmax1 (128) ----
__global__ __launch_bounds__(256) void k_sort_cmax(const int* __restrict__ ei,
    const int* __restrict__ rowptr, int* __restrict__ bcur,
    int2* __restrict__ tmp, int E, int Etot, int NB,
    int nbS, const float* __restrict__ al1, unsigned* __restrict__ almax1, int totalC){
  __shared__ int hist[MAXB];
  __shared__ int hbase[MAXB];
  __shared__ int2 stage[SB];
  if ((int)blockIdx.x >= nbS){
    int bid = (int)blockIdx.x - nbS;
    int tid = bid*256 + threadIdx.x;
    int stride = 128*256;
    float mx = -1e30f;
    for (int i = tid; i < totalC; i += stride)
      mx = fmaxf(mx, al1[i]);
    mx = fmaxf(mx, __shfl_xor(mx, 4));
    mx = fmaxf(mx, __shfl_xor(mx, 8));
    mx = fmaxf(mx, __shfl_xor(mx, 16));
    mx = fmaxf(mx, __shfl_xor(mx, 32));
    int lane = threadIdx.x & 63;
    if (lane < 4) atomicMax(&almax1[lane], fenc(mx));
    return;
  }
  int base_e = blockIdx.x * SB;
  int cnt = Etot - base_e; if (cnt > SB) cnt = SB;
  for (int i = threadIdx.x; i < NB; i += 256) hist[i] = 0;
  __syncthreads();
  for (int i = threadIdx.x; i < cnt; i += 256){
    int e = base_e + i;
    int s = (e < E) ? ei[e]     : (e - E);
    int d = (e < E) ? ei[E + e] : (e - E);
    stage[i] = make_int2(s, d);
    atomicAdd(&hist[d>>BSH], 1);
  }
  __syncthreads();
  for (int i = threadIdx.x; i < NB; i += 256){
    int c = hist[i];
    hbase[i] = c ? (rowptr[i<<BSH] + atomicAdd(&bcur[i*16], c)) : 0;
    hist[i] = 0;
  }
  __syncthreads();
  for (int i = threadIdx.x; i < cnt; i += 256){
    int2 sd = stage[i];
    int b = sd.y >> BSH;
    int off = atomicAdd(&hist[b], 1);
    tmp[hbase[b] + off] = sd;
  }
}

// ---- pass 2: per-bucket LDS scatter -> coalesced csr_src AND csr_dst ----
__global__ __launch_bounds__(256) void k_fill2(const int* __restrict__ rowptr,
    const int2* __restrict__ tmp, int* __restrict__ csr_src,
    int* __restrict__ csr_dst, int* __restrict__ cursor, int n, int NB){
  int b = blockIdx.x;
  int node0 = b << BSH;
  int node1 = node0 + (1<<BSH); if (node1 > n) node1 = n;
  int base = rowptr[node0];
  int endp = rowptr[node1];
  int size = endp - base;
  __shared__ int lcur[1<<BSH];
  __shared__ int2 lout[BCAP];
  if (size <= BCAP){
    if (threadIdx.x < (1<<BSH)){
      int nd = node0 + threadIdx.x;
      lcur[threadIdx.x] = (nd < node1) ? rowptr[nd] - base : 0;
    }
    __syncthreads();
    for (int i = threadIdx.x; i < size; i += 256){
      int2 sd = tmp[base + i];
      int rel = atomicAdd(&lcur[sd.y & ((1<<BSH)-1)], 1);
      lout[rel] = sd;
    }
    __syncthreads();
    for (int i = threadIdx.x; i < size; i += 256){
      int2 sd = lout[i];
      csr_src[base + i] = sd.x;
      csr_dst[base + i] = sd.y;
    }
  } else {
    for (int i = threadIdx.x; i < size; i += 256){
      int2 sd = tmp[base + i];
      int pos = atomicAdd(&cursor[sd.y], 1);
      csr_src[pos] = sd.x;
      csr_dst[pos] = sd.y;
    }
  }
}

// ---- layer-1 GAT + fused x1@W2: wave/node; 16-edge unroll; fast ELU ----
__global__ __launch_bounds__(256) void k_gat1(const int* __restrict__ rowptr,
    const int* __restrict__ csr_src, const float* __restrict__ al,
    const float* __restrict__ ar, const unsigned* __restrict__ almax,
    const unsigned char* __restrict__ h1, const float* __restrict__ b1,
    const float* __restrict__ W2, const float* __restrict__ as2,
    const float* __restrict__ ad2, __half* __restrict__ h2,
    float* __restrict__ al2, float* __restrict__ ar2, int n){
  __shared__ float w2s[1024];
  for (int a = threadIdx.x; a < 1024; a += 256){
    int fs = a & 15;
    int es = (a >> 4) & 3;
    int r  = a >> 6;
    int kk = r >> 1;
    int jj = r & 1;
    w2s[a] = W2[(fs*8 + kk)*C2N + es*2 + jj];
  }
  __syncthreads();
  int node = blockIdx.x*4 + (threadIdx.x >> 6);
  if (node >= n) return;
  int lane = threadIdx.x & 63;
  int es = lane >> 4;
  int fs = lane & 15;
  int h  = fs >> 2;
  int f0 = fs << 3;
  int beg = rowptr[node], end = rowptr[node+1];
  float ard = ar[node*4 + h];
  float ub = fdec(almax[h]) + ard;
  ub = ub > 0.f ? ub : SLOPE*ub;
  float a0=0.f,a1=0.f,a2=0.f,a3=0.f,a4=0.f,a5=0.f,a6=0.f,a7=0.f,den=0.f;
  int c = beg;
  #define EDGE_GRP(SV, ALV, HV) { \
    float v_ = ALV + ard; v_ = v_ > 0.f ? v_ : SLOPE*v_; \
    float w_ = __expf(v_ - ub); \
    den += w_; \
    floatx2 r0_ = __builtin_amdgcn_cvt_pk_f32_fp8(HV.x, false); \
    floatx2 r1_ = __builtin_amdgcn_cvt_pk_f32_fp8(HV.x, true); \
    floatx2 r2_ = __builtin_amdgcn_cvt_pk_f32_fp8(HV.y, false); \
    floatx2 r3_ = __builtin_amdgcn_cvt_pk_f32_fp8(HV.y, true); \
    a0 += w_*r0_.x; a1 += w_*r0_.y; a2 += w_*r1_.x; a3 += w_*r1_.y; \
    a4 += w_*r2_.x; a5 += w_*r2_.y; a6 += w_*r3_.x; a7 += w_*r3_.y; }
  for (; c + 16 <= end; c += 16){
    int sA = csr_src[c + es];
    int sB = csr_src[c + 4 + es];
    int sC = csr_src[c + 8 + es];
    int sD = csr_src[c + 12 + es];
    float alA = al[sA*4 + h];
    float alB = al[sB*4 + h];
    float alC = al[sC*4 + h];
    float alD = al[sD*4 + h];
    uint2 hvA = *(const uint2*)&h1[((size_t)sA<<7) + f0];
    uint2 hvB = *(const uint2*)&h1[((size_t)sB<<7) + f0];
    uint2 hvC = *(const uint2*)&h1[((size_t)sC<<7) + f0];
    uint2 hvD = *(const uint2*)&h1[((size_t)sD<<7) + f0];
    EDGE_GRP(sA, alA, hvA)
    EDGE_GRP(sB, alB, hvB)
    EDGE_GRP(sC, alC, hvC)
    EDGE_GRP(sD, alD, hvD)
  }
  for (; c + 8 <= end; c += 8){
    int sA = csr_src[c + es];
    int sB = csr_src[c + 4 + es];
    float alA = al[sA*4 + h];
    float alB = al[sB*4 + h];
    uint2 hvA = *(const uint2*)&h1[((size_t)sA<<7) + f0];
    uint2 hvB = *(const uint2*)&h1[((size_t)sB<<7) + f0];
    EDGE_GRP(sA, alA, hvA)
    EDGE_GRP(sB, alB, hvB)
  }
  #undef EDGE_GRP
  for (; c < end; c += 4){
    int idx = c + es;
    bool ok = idx < end;
    int s = csr_src[ok ? idx : end-1];
    float alv = al[s*4 + h];
    float v = alv + ard; v = v > 0.f ? v : SLOPE*v;
    float wv = __expf(v - ub);
    wv = ok ? wv : 0.f;
    den += wv;
    uint2 hv = *(const uint2*)&h1[((size_t)s<<7) + f0];
    floatx2 p0 = __builtin_amdgcn_cvt_pk_f32_fp8(hv.x, false);
    floatx2 p1 = __builtin_amdgcn_cvt_pk_f32_fp8(hv.x, true);
    floatx2 p2 = __builtin_amdgcn_cvt_pk_f32_fp8(hv.y, false);
    floatx2 p3 = __builtin_amdgcn_cvt_pk_f32_fp8(hv.y, true);
    a0 += wv*p0.x; a1 += wv*p0.y; a2 += wv*p1.x; a3 += wv*p1.y;
    a4 += wv*p2.x; a5 += wv*p2.y; a6 += wv*p3.x; a7 += wv*p3.y;
  }
  #define RED2(X) { X += __shfl_xor(X,16); X += __shfl_xor(X,32); }
  RED2(a0) RED2(a1) RED2(a2) RED2(a3) RED2(a4) RED2(a5) RED2(a6) RED2(a7) RED2(den)
  float inv = 1.f / (den + 1e-16f);
  float4 bA = *(const float4*)&b1[f0];
  float4 bB = *(const float4*)&b1[f0+4];
  float o0 = a0*inv + bA.x, o1 = a1*inv + bA.y;
  float o2 = a2*inv + bA.z, o3 = a3*inv + bA.w;
  float o4 = a4*inv + bB.x, o5 = a5*inv + bB.y;
  float o6 = a6*inv + bB.z, o7 = a7*inv + bB.w;
  o0 = o0 > 0.f ? o0 : __expf(o0) - 1.f;
  o1 = o1 > 0.f ? o1 : __expf(o1) - 1.f;
  o2 = o2 > 0.f ? o2 : __expf(o2) - 1.f;
  o3 = o3 > 0.f ? o3 : __expf(o3) - 1.f;
  o4 = o4 > 0.f ? o4 : __expf(o4) - 1.f;
  o5 = o5 > 0.f ? o5 : __expf(o5) - 1.f;
  o6 = o6 > 0.f ? o6 : __expf(o6) - 1.f;
  o7 = o7 > 0.f ? o7 : __expf(o7) - 1.f;
  const float* wG = w2s + es*16 + fs;
  float gA = 0.f, gB = 0.f;
  gA += o0*wG[0];   gB += o0*wG[64];
  gA += o1*wG[128]; gB += o1*wG[192];
  gA += o2*wG[256]; gB += o2*wG[320];
  gA += o3*wG[384]; gB += o3*wG[448];
  gA += o4*wG[512]; gB += o4*wG[576];
  gA += o5*wG[640]; gB += o5*wG[704];
  gA += o6*wG[768]; gB += o6*wG[832];
  gA += o7*wG[896]; gB += o7*wG[960];
  #define RED4(X) { X += __shfl_xor(X,1); X += __shfl_xor(X,2); \
                    X += __shfl_xor(X,4); X += __shfl_xor(X,8); }
  RED4(gA) RED4(gB)
  #undef RED4
  float pal = gA*as2[es*2] + gB*as2[es*2+1];
  float par = gA*ad2[es*2] + gB*ad2[es*2+1];
  RED2(pal) RED2(par)
  #undef RED2
  if (fs == 0){
    *(__half2*)&h2[((size_t)node<<3) + es*2] = __floats2half2_rn(gA, gB);
  }
  if (lane == 0){
    al2[node] = pal;
    ar2[node] = par;
  }
}

// ---- layer-2 GAT, edge-parallel: lane = one CSR edge; segmented wave scan ----
__global__ __launch_bounds__(256) void k_gat2e(const int* __restrict__ csr_src,
    const int* __restrict__ csr_dst, const float* __restrict__ al,
    const float* __restrict__ ar, const unsigned* __restrict__ almax,
    const __half* __restrict__ h2, float* __restrict__ nacc,
    float* __restrict__ nden, int Etot){
  int e = blockIdx.x*256 + threadIdx.x;
  int lane = threadIdx.x & 63;
  bool ok = e < Etot;
  int s = ok ? csr_src[e] : 0;
  int d = ok ? csr_dst[e] : -1;
  float w = 0.f;
  if (ok){
    float ardv = ar[d];
    float v = al[s] + ardv; v = v > 0.f ? v : SLOPE*v;
    float ub = fdec(almax[0]) + ardv; ub = ub > 0.f ? ub : SLOPE*ub;
    w = __expf(v - ub);
  }
  float2 h01 = {0,0}, h23 = {0,0}, h45 = {0,0}, h67 = {0,0};
  if (ok){
    uint4 hv = *(const uint4*)&h2[((size_t)s<<3)];
    h01 = h2f2(hv.x); h23 = h2f2(hv.y); h45 = h2f2(hv.z); h67 = h2f2(hv.w);
  }
  float a0 = w*h01.x, a1 = w*h01.y, a2 = w*h23.x, a3 = w*h23.y;
  float a4 = w*h45.x, a5 = w*h45.y, a6 = w*h67.x, a7 = w*h67.y;
  float den = w;
  #pragma unroll
  for (int off = 1; off < 64; off <<= 1){
    int du = __shfl_up(d, off);
    bool add = (lane >= off) && (du == d);
    float t;
    t = __shfl_up(a0, off); if (add) a0 += t;
    t = __shfl_up(a1, off); if (add) a1 += t;
    t = __shfl_up(a2, off); if (add) a2 += t;
    t = __shfl_up(a3, off); if (add) a3 += t;
    t = __shfl_up(a4, off); if (add) a4 += t;
    t = __shfl_up(a5, off); if (add) a5 += t;
    t = __shfl_up(a6, off); if (add) a6 += t;
    t = __shfl_up(a7, off); if (add) a7 += t;
    t = __shfl_up(den, off); if (add) den += t;
  }
  int dn = __shfl_down(d, 1);
  bool tail = (lane == 63) || (dn != d);
  if (tail && d >= 0){
    float* np = nacc + ((size_t)d<<3);
    atomicAdd(np+0, a0); atomicAdd(np+1, a1);
    atomicAdd(np+2, a2); atomicAdd(np+3, a3);
    atomicAdd(np+4, a4); atomicAdd(np+5, a5);
    atomicAdd(np+6, a6); atomicAdd(np+7, a7);
    atomicAdd(&nden[d], den);
  }
}

// ---- finalize layer 2 + pool scatter + last-block log_softmax ----
__global__ __launch_bounds__(256) void k_fin2f(const float* __restrict__ nacc,
    const float* __restrict__ nden, const float* __restrict__ b2,
    const int* __restrict__ batch, float* __restrict__ pooled,
    float* __restrict__ cnt, float* __restrict__ out, int n, int G,
    int* __restrict__ done, int nblocks){
  int t = blockIdx.x*256 + threadIdx.x;
  int node = t >> 3, j = t & 7;
  if (node < n){
    float o = nacc[t] / (nden[node] + 1e-16f) + b2[j];
    int g = batch[node];
    atomicAdd(&pooled[g*C2N + j], o);
    if (j == 0) atomicAdd(&cnt[g], 1.f);
  }
  __threadfence();
  __syncthreads();
  __shared__ int lastBlock;
  if (threadIdx.x == 0)
    lastBlock = (atomicAdd(done, 1) == nblocks - 1);
  __syncthreads();
  if (lastBlock){
    __threadfence();
    const volatile float* vp = (const volatile float*)pooled;
    const volatile float* vc = (const volatile float*)cnt;
    for (int g = threadIdx.x; g < G; g += 256){
      float c = vc[g]; c = c > 1.f ? c : 1.f;
      float p[8]; float mx = -1e30f;
      #pragma unroll
      for (int jj = 0; jj < 8; ++jj){ p[jj] = vp[g*8+jj] / c; mx = fmaxf(mx, p[jj]); }
      float s = 0.f;
      #pragma unroll
      for (int jj = 0; jj < 8; ++jj) s += expf(p[jj]-mx);
      float lse = mx + logf(s);
      #pragma unroll
      for (int jj = 0; jj < 8; ++jj) out[g*8+jj] = p[jj] - lse;
    }
  }
}

extern "C" void kernel_launch(void* const* d_in, const int* in_sizes, int n_in,
                              void* d_out, int out_size, void* d_ws, size_t ws_size,
                              hipStream_t stream){
  const float* x    = (const float*)d_in[0];
  const float* gam  = (const float*)d_in[1];
  const float* bet  = (const float*)d_in[2];
  const float* W1   = (const float*)d_in[3];
  const float* as1  = (const float*)d_in[4];
  const float* ad1  = (const float*)d_in[5];
  const float* b1   = (const float*)d_in[6];
  const float* W2   = (const float*)d_in[7];
  const float* as2  = (const float*)d_in[8];
  const float* ad2  = (const float*)d_in[9];
  const float* b2   = (const float*)d_in[10];
  const int*   ei   = (const int*)d_in[11];
  const int*   batch= (const int*)d_in[12];

  int N = in_sizes[0] / F1;
  int E = in_sizes[11] / 2;
  int G = out_size / C2N;
  int Etot = E + N;
  int nb = (N + 1023) / 1024;
  int NB = (N + (1<<BSH) - 1) >> BSH;
  int nbG = (N + 15) / 16;
  int nbS = (Etot + SB - 1) / SB;
  int nbF = ((N*C2N) + 255) / 256;

  char* base = (char*)d_ws;
  auto alloc = [&](size_t bytes)->char*{
    char* p = base; base += (bytes + 15) & ~15ull; return p;
  };

  // ---- region A: zeroed every launch ----
  char* A0 = base;
  float*    sum     = (float*)alloc(128*4);
  float*    sumsq   = (float*)alloc(128*4);
  int*      deg     = (int*)alloc((size_t)N*4);
  float*    pooled  = (float*)alloc((size_t)G*C2N*4);
  float*    cnt     = (float*)alloc((size_t)G*4);
  unsigned* almax1u = (unsigned*)alloc(16);
  unsigned* almax2u = (unsigned*)alloc(16);
  float*    nacc    = (float*)alloc((size_t)N*C2N*4);
  float*    nden    = (float*)alloc((size_t)N*4);
  int*      bcur    = (int*)alloc((size_t)NB*64);   // relative cursors
  int*      done    = (int*)alloc(16);
  size_t Abytes = (size_t)(base - A0);
  // ---- rest ----
  int*     csr_src = (int*)alloc((size_t)Etot*4);
  int*     csr_dst = (int*)alloc((size_t)Etot*4);
  int2*    tmp     = (int2*)alloc((size_t)Etot*8);
  float*   ab      = (float*)alloc(256*4);
  int*     rowptr  = (int*)alloc(((size_t)N+4)*4);
  int*     cursor  = (int*)alloc((size_t)N*4);
  int*     bsum    = (int*)alloc((size_t)nb*4);
  unsigned char* h1 = (unsigned char*)alloc((size_t)N*F1);
  float*   al1     = (float*)alloc((size_t)N*4*4);
  float*   ar1     = (float*)alloc((size_t)N*4*4);
  __half*  h2      = (__half*)alloc((size_t)N*C2N*2);
  float*   al2     = (float*)alloc((size_t)N*4);
  float*   ar2     = (float*)alloc((size_t)N*4);

  hipMemsetAsync(A0, 0, Abytes, stream);

  k_bn_deg<<<256 + (E + 255)/256, 256, 0, stream>>>(x, sum, sumsq, N, ei, deg, E);
  k_scan_a_bn<<<nb + 1, 256, 0, stream>>>(deg, rowptr, bsum, N, sum, sumsq, gam, bet, ab);
  k_gemm1_scanc<<<nbG + nb, 256, 0, stream>>>(x, ab, W1, as1, ad1, h1, al1, ar1, N,
                                              rowptr, cursor, bsum, nb, nbG);
  k_sort_cmax<<<nbS + 128, 256, 0, stream>>>(ei, rowptr, bcur, tmp, E, Etot, NB,
                                             nbS, al1, almax1u, N*4);
  k_fill2<<<NB, 256, 0, stream>>>(rowptr, tmp, csr_src, csr_dst, cursor, N, NB);
  k_gat1<<<(N + 3)/4, 256, 0, stream>>>(rowptr, csr_src, al1, ar1, almax1u, h1, b1,
                                        W2, as2, ad2, h2, al2, ar2, N);
  k_colmax<<<64, 256, 0, stream>>>(al2, almax2u, N, 1);
  k_gat2e<<<(Etot + 255)/256, 256, 0, stream>>>(csr_src, csr_dst, al2, ar2, almax2u, h2, nacc, nden, Etot);
  k_fin2f<<<nbF, 256, 0, stream>>>(nacc, nden, b2, batch, pooled, cnt,
                                   (float*)d_out, N, G, done, nbF);
}

// Round 23
// 257.524 us; speedup vs baseline: 1.2738x; 1.2738x over previous
//
#include <hip/hip_runtime.h>
#include <hip/hip_fp16.h>
#include <math.h>

#define F1 128
#define C2N 8
#define SLOPE 0.2f
#define EPSBN 1e-5f
#define BCAP 4096
#define SB 4096
#define BSH 7      // 128 nodes per bucket
#define MAXB 1024

typedef float floatx2 __attribute__((ext_vector_type(2)));

__device__ __forceinline__ unsigned fenc(float f){
  unsigned u = __float_as_uint(f);
  return (u & 0x80000000u) ? ~u : (u | 0x80000000u);
}
__device__ __forceinline__ float fdec(unsigned u){
  return (u & 0x80000000u) ? __uint_as_float(u & 0x7FFFFFFFu) : __uint_as_float(~u);
}
__device__ __forceinline__ float2 h2f2(unsigned u){
  __half2 h = *(__half2*)&u;
  return __half22float2(h);
}

// ---- fused: BatchNorm stats (blocks 0..255) || dst-degree histogram (rest) ----
__global__ __launch_bounds__(256) void k_bn_deg(const float* __restrict__ x,
    float* __restrict__ sum, float* __restrict__ sumsq, int n,
    const int* __restrict__ ei, int* __restrict__ deg, int E){
  if ((int)blockIdx.x >= 256){
    int e = ((int)blockIdx.x - 256)*256 + threadIdx.x;
    if (e < E) atomicAdd(&deg[ei[E + e]], 1);
    return;
  }
  int t  = threadIdx.x;
  int c4 = (t & 31) * 4;
  int rg = t >> 5;
  float4 s = {0,0,0,0}, q = {0,0,0,0};
  for (int r = blockIdx.x*8 + rg; r < n; r += 2048){
    float4 v = *(const float4*)&x[(size_t)r*F1 + c4];
    s.x += v.x; s.y += v.y; s.z += v.z; s.w += v.w;
    q.x += v.x*v.x; q.y += v.y*v.y; q.z += v.z*v.z; q.w += v.w*v.w;
  }
  s.x += __shfl_xor(s.x, 32); s.y += __shfl_xor(s.y, 32);
  s.z += __shfl_xor(s.z, 32); s.w += __shfl_xor(s.w, 32);
  q.x += __shfl_xor(q.x, 32); q.y += __shfl_xor(q.y, 32);
  q.z += __shfl_xor(q.z, 32); q.w += __shfl_xor(q.w, 32);
  __shared__ float red[2][4][F1];
  int w = t >> 6;
  int l = t & 63;
  if (l < 32){
    *(float4*)&red[0][w][l*4] = s;
    *(float4*)&red[1][w][l*4] = q;
  }
  __syncthreads();
  if (t < 128){
    float a = red[0][0][t] + red[0][1][t] + red[0][2][t] + red[0][3][t];
    atomicAdd(&sum[t], a);
  } else {
    int f = t - 128;
    float a = red[1][0][f] + red[1][1][f] + red[1][2][f] + red[1][3][f];
    atomicAdd(&sumsq[f], a);
  }
}

// ---- fused: scan A (blocks 0..nb-1) || bn_final (last block) ----
__global__ __launch_bounds__(256) void k_scan_a_bn(const int* __restrict__ deg,
    int* __restrict__ rowptr, int* __restrict__ bsum, int n,
    const float* __restrict__ sum, const float* __restrict__ sumsq,
    const float* __restrict__ gamma, const float* __restrict__ beta,
    float* __restrict__ ab){
  int nbS = gridDim.x - 1;
  if ((int)blockIdx.x == nbS){
    int f = threadIdx.x;
    if (f < 128){
      float inv_n = 1.f / (float)n;
      float mean = sum[f] * inv_n;
      float var  = sumsq[f] * inv_n - mean*mean;
      float inv  = rsqrtf(var + EPSBN);
      float a = inv * gamma[f];
      ab[f]      = a;
      ab[F1 + f] = beta[f] - mean*a;
    }
    return;
  }
  int t = threadIdx.x;
  int base = blockIdx.x*1024 + t*4;
  int4 v = {0,0,0,0};
  if (base + 3 < n){
    v = *(const int4*)&deg[base];
    v.x += 1; v.y += 1; v.z += 1; v.w += 1;
  } else {
    if (base   < n) v.x = deg[base]   + 1;
    if (base+1 < n) v.y = deg[base+1] + 1;
    if (base+2 < n) v.z = deg[base+2] + 1;
    if (base+3 < n) v.w = deg[base+3] + 1;
  }
  int s = v.x + v.y + v.z + v.w;
  __shared__ int ls[256];
  ls[t] = s; __syncthreads();
  for (int off = 1; off < 256; off <<= 1){
    int u = (t >= off) ? ls[t-off] : 0;
    __syncthreads();
    ls[t] += u;
    __syncthreads();
  }
  int ex = ls[t] - s;
  if (t == 255) bsum[blockIdx.x] = ls[255];
  int4 w;
  w.x = ex;
  w.y = ex + v.x;
  w.z = w.y + v.y;
  w.w = w.z + v.z;
  if (base + 3 < n) *(int4*)&rowptr[base] = w;
  else {
    if (base   < n) rowptr[base]   = w.x;
    if (base+1 < n) rowptr[base+1] = w.y;
    if (base+2 < n) rowptr[base+2] = w.z;
    if (base+3 < n) rowptr[base+3] = w.w;
  }
}

// ---- fused: normalize + x@W1 + al1/ar1 (blocks < nbG) || scan C (rest) ----
__global__ __launch_bounds__(256) void k_gemm1_scanc(const float* __restrict__ x,
    const float* __restrict__ ab, const float* __restrict__ W1,
    const float* __restrict__ asrc, const float* __restrict__ adst,
    unsigned char* __restrict__ h1, float* __restrict__ al, float* __restrict__ ar,
    int n, int* __restrict__ rowptr, int* __restrict__ cursor,
    const int* __restrict__ bsum, int nb, int nbG){
  if ((int)blockIdx.x >= nbG){
    int sb = (int)blockIdx.x - nbG;      // scan-C block id, 0..nb-1
    int t = threadIdx.x;
    __shared__ int s_boff;
    if (t < 64){
      int val = 0;
      for (int i = t; i < sb; i += 64) val += bsum[i];
      #pragma unroll
      for (int m = 1; m < 64; m <<= 1) val += __shfl_xor(val, m);
      if (t == 0) s_boff = val;
    }
    __syncthreads();
    int boff = s_boff;
    if (t == 0 && sb == nb - 1)
      rowptr[n] = boff + bsum[sb];
    int base = sb*1024 + t*4;
    if (base + 3 < n){
      int4 v = *(int4*)&rowptr[base];
      v.x += boff; v.y += boff; v.z += boff; v.w += boff;
      *(int4*)&rowptr[base] = v;
      *(int4*)&cursor[base] = v;
    } else {
      for (int k = 0; k < 4; ++k)
        if (base + k < n){
          int v = rowptr[base+k] + boff;
          rowptr[base+k] = v; cursor[base+k] = v;
        }
    }
    return;
  }
  const int j    = threadIdx.x & 127;
  const int half = threadIdx.x >> 7;
  const int r0   = blockIdx.x * 16 + half*8;
  __shared__ float xs[16][F1];
  float A = ab[j], B = ab[F1 + j];
  int nr = n - r0; if (nr > 8) nr = 8; if (nr < 0) nr = 0;
  for (int rr = 0; rr < nr; ++rr)
    xs[half*8+rr][j] = x[(size_t)(r0+rr)*F1 + j] * A + B;
  __syncthreads();
  float acc[8] = {0,0,0,0,0,0,0,0};
  for (int k = 0; k < F1; ++k){
    float w = W1[k*F1 + j];
    #pragma unroll
    for (int rr = 0; rr < 8; ++rr) acc[rr] += xs[half*8+rr][k] * w;
  }
  float as = asrc[j], ad = adst[j];
  for (int rr = 0; rr < nr; ++rr){
    float hv = acc[rr];
    int pk = __builtin_amdgcn_cvt_pk_fp8_f32(hv, hv, 0, false);
    h1[(size_t)(r0+rr)*F1 + j] = (unsigned char)(pk & 0xFF);
    float vs = hv*as, vd = hv*ad;
    #pragma unroll
    for (int mk = 1; mk < 32; mk <<= 1){
      vs += __shfl_xor(vs, mk);
      vd += __shfl_xor(vd, mk);
    }
    if ((j & 31) == 0){
      al[(r0+rr)*4 + (j>>5)] = vs;
      ar[(r0+rr)*4 + (j>>5)] = vd;
    }
  }
}

// ---- global column max (standalone; layer 2) ----
__global__ __launch_bounds__(256) void k_colmax(const float* __restrict__ v,
    unsigned* __restrict__ out, int total, int H){
  int tid = blockIdx.x*256 + threadIdx.x;
  int stride = gridDim.x*256;
  float mx = -1e30f;
  for (int i = tid; i < total; i += stride)
    mx = fmaxf(mx, v[i]);
  for (int m = H; m < 64; m <<= 1)
    mx = fmaxf(mx, __shfl_xor(mx, m));
  int lane = threadIdx.x & 63;
  if (lane < H) atomicMax(&out[lane], fenc(mx));
}

// ---- fused: counting sort (blocks < nbS, relative bcur) || colmax1 (128) ----
__global__ __launch_bounds__(256) void k_sort_cmax(const int* __restrict__ ei,
    const int* __restrict__ rowptr, int* __restrict__ bcur,
    int2* __restrict__ tmp, int E, int Etot, int NB,
    int nbS, const float* __restrict__ al1, unsigned* __restrict__ almax1, int totalC){
  __shared__ int hist[MAXB];
  __shared__ int hbase[MAXB];
  __shared__ int2 stage[SB];
  if ((int)blockIdx.x >= nbS){
    int bid = (int)blockIdx.x - nbS;
    int tid = bid*256 + threadIdx.x;
    int stride = 128*256;
    float mx = -1e30f;
    for (int i = tid; i < totalC; i += stride)
      mx = fmaxf(mx, al1[i]);
    mx = fmaxf(mx, __shfl_xor(mx, 4));
    mx = fmaxf(mx, __shfl_xor(mx, 8));
    mx = fmaxf(mx, __shfl_xor(mx, 16));
    mx = fmaxf(mx, __shfl_xor(mx, 32));
    int lane = threadIdx.x & 63;
    if (lane < 4) atomicMax(&almax1[lane], fenc(mx));
    return;
  }
  int base_e = blockIdx.x * SB;
  int cnt = Etot - base_e; if (cnt > SB) cnt = SB;
  for (int i = threadIdx.x; i < NB; i += 256) hist[i] = 0;
  __syncthreads();
  for (int i = threadIdx.x; i < cnt; i += 256){
    int e = base_e + i;
    int s = (e < E) ? ei[e]     : (e - E);
    int d = (e < E) ? ei[E + e] : (e - E);
    stage[i] = make_int2(s, d);
    atomicAdd(&hist[d>>BSH], 1);
  }
  __syncthreads();
  for (int i = threadIdx.x; i < NB; i += 256){
    int c = hist[i];
    hbase[i] = c ? (rowptr[i<<BSH] + atomicAdd(&bcur[i*16], c)) : 0;
    hist[i] = 0;
  }
  __syncthreads();
  for (int i = threadIdx.x; i < cnt; i += 256){
    int2 sd = stage[i];
    int b = sd.y >> BSH;
    int off = atomicAdd(&hist[b], 1);
    tmp[hbase[b] + off] = sd;
  }
}

// ---- pass 2: per-bucket LDS scatter -> coalesced csr_src AND csr_dst ----
__global__ __launch_bounds__(256) void k_fill2(const int* __restrict__ rowptr,
    const int2* __restrict__ tmp, int* __restrict__ csr_src,
    int* __restrict__ csr_dst, int* __restrict__ cursor, int n, int NB){
  int b = blockIdx.x;
  int node0 = b << BSH;
  int node1 = node0 + (1<<BSH); if (node1 > n) node1 = n;
  int base = rowptr[node0];
  int endp = rowptr[node1];
  int size = endp - base;
  __shared__ int lcur[1<<BSH];
  __shared__ int2 lout[BCAP];
  if (size <= BCAP){
    if (threadIdx.x < (1<<BSH)){
      int nd = node0 + threadIdx.x;
      lcur[threadIdx.x] = (nd < node1) ? rowptr[nd] - base : 0;
    }
    __syncthreads();
    for (int i = threadIdx.x; i < size; i += 256){
      int2 sd = tmp[base + i];
      int rel = atomicAdd(&lcur[sd.y & ((1<<BSH)-1)], 1);
      lout[rel] = sd;
    }
    __syncthreads();
    for (int i = threadIdx.x; i < size; i += 256){
      int2 sd = lout[i];
      csr_src[base + i] = sd.x;
      csr_dst[base + i] = sd.y;
    }
  } else {
    for (int i = threadIdx.x; i < size; i += 256){
      int2 sd = tmp[base + i];
      int pos = atomicAdd(&cursor[sd.y], 1);
      csr_src[pos] = sd.x;
      csr_dst[pos] = sd.y;
    }
  }
}

// ---- layer-1 GAT + fused x1@W2: wave/node; 16-edge unroll; fast ELU ----
__global__ __launch_bounds__(256) void k_gat1(const int* __restrict__ rowptr,
    const int* __restrict__ csr_src, const float* __restrict__ al,
    const float* __restrict__ ar, const unsigned* __restrict__ almax,
    const unsigned char* __restrict__ h1, const float* __restrict__ b1,
    const float* __restrict__ W2, const float* __restrict__ as2,
    const float* __restrict__ ad2, __half* __restrict__ h2,
    float* __restrict__ al2, float* __restrict__ ar2, int n){
  __shared__ float w2s[1024];
  for (int a = threadIdx.x; a < 1024; a += 256){
    int fs = a & 15;
    int es = (a >> 4) & 3;
    int r  = a >> 6;
    int kk = r >> 1;
    int jj = r & 1;
    w2s[a] = W2[(fs*8 + kk)*C2N + es*2 + jj];
  }
  __syncthreads();
  int node = blockIdx.x*4 + (threadIdx.x >> 6);
  if (node >= n) return;
  int lane = threadIdx.x & 63;
  int es = lane >> 4;
  int fs = lane & 15;
  int h  = fs >> 2;
  int f0 = fs << 3;
  int beg = rowptr[node], end = rowptr[node+1];
  float ard = ar[node*4 + h];
  float ub = fdec(almax[h]) + ard;
  ub = ub > 0.f ? ub : SLOPE*ub;
  float a0=0.f,a1=0.f,a2=0.f,a3=0.f,a4=0.f,a5=0.f,a6=0.f,a7=0.f,den=0.f;
  int c = beg;
  #define EDGE_GRP(SV, ALV, HV) { \
    float v_ = ALV + ard; v_ = v_ > 0.f ? v_ : SLOPE*v_; \
    float w_ = __expf(v_ - ub); \
    den += w_; \
    floatx2 r0_ = __builtin_amdgcn_cvt_pk_f32_fp8(HV.x, false); \
    floatx2 r1_ = __builtin_amdgcn_cvt_pk_f32_fp8(HV.x, true); \
    floatx2 r2_ = __builtin_amdgcn_cvt_pk_f32_fp8(HV.y, false); \
    floatx2 r3_ = __builtin_amdgcn_cvt_pk_f32_fp8(HV.y, true); \
    a0 += w_*r0_.x; a1 += w_*r0_.y; a2 += w_*r1_.x; a3 += w_*r1_.y; \
    a4 += w_*r2_.x; a5 += w_*r2_.y; a6 += w_*r3_.x; a7 += w_*r3_.y; }
  for (; c + 16 <= end; c += 16){
    int sA = csr_src[c + es];
    int sB = csr_src[c + 4 + es];
    int sC = csr_src[c + 8 + es];
    int sD = csr_src[c + 12 + es];
    float alA = al[sA*4 + h];
    float alB = al[sB*4 + h];
    float alC = al[sC*4 + h];
    float alD = al[sD*4 + h];
    uint2 hvA = *(const uint2*)&h1[((size_t)sA<<7) + f0];
    uint2 hvB = *(const uint2*)&h1[((size_t)sB<<7) + f0];
    uint2 hvC = *(const uint2*)&h1[((size_t)sC<<7) + f0];
    uint2 hvD = *(const uint2*)&h1[((size_t)sD<<7) + f0];
    EDGE_GRP(sA, alA, hvA)
    EDGE_GRP(sB, alB, hvB)
    EDGE_GRP(sC, alC, hvC)
    EDGE_GRP(sD, alD, hvD)
  }
  for (; c + 8 <= end; c += 8){
    int sA = csr_src[c + es];
    int sB = csr_src[c + 4 + es];
    float alA = al[sA*4 + h];
    float alB = al[sB*4 + h];
    uint2 hvA = *(const uint2*)&h1[((size_t)sA<<7) + f0];
    uint2 hvB = *(const uint2*)&h1[((size_t)sB<<7) + f0];
    EDGE_GRP(sA, alA, hvA)
    EDGE_GRP(sB, alB, hvB)
  }
  #undef EDGE_GRP
  for (; c < end; c += 4){
    int idx = c + es;
    bool ok = idx < end;
    int s = csr_src[ok ? idx : end-1];
    float alv = al[s*4 + h];
    float v = alv + ard; v = v > 0.f ? v : SLOPE*v;
    float wv = __expf(v - ub);
    wv = ok ? wv : 0.f;
    den += wv;
    uint2 hv = *(const uint2*)&h1[((size_t)s<<7) + f0];
    floatx2 p0 = __builtin_amdgcn_cvt_pk_f32_fp8(hv.x, false);
    floatx2 p1 = __builtin_amdgcn_cvt_pk_f32_fp8(hv.x, true);
    floatx2 p2 = __builtin_amdgcn_cvt_pk_f32_fp8(hv.y, false);
    floatx2 p3 = __builtin_amdgcn_cvt_pk_f32_fp8(hv.y, true);
    a0 += wv*p0.x; a1 += wv*p0.y; a2 += wv*p1.x; a3 += wv*p1.y;
    a4 += wv*p2.x; a5 += wv*p2.y; a6 += wv*p3.x; a7 += wv*p3.y;
  }
  #define RED2(X) { X += __shfl_xor(X,16); X += __shfl_xor(X,32); }
  RED2(a0) RED2(a1) RED2(a2) RED2(a3) RED2(a4) RED2(a5) RED2(a6) RED2(a7) RED2(den)
  float inv = 1.f / (den + 1e-16f);
  float4 bA = *(const float4*)&b1[f0];
  float4 bB = *(const float4*)&b1[f0+4];
  float o0 = a0*inv + bA.x, o1 = a1*inv + bA.y;
  float o2 = a2*inv + bA.z, o3 = a3*inv + bA.w;
  float o4 = a4*inv + bB.x, o5 = a5*inv + bB.y;
  float o6 = a6*inv + bB.z, o7 = a7*inv + bB.w;
  o0 = o0 > 0.f ? o0 : __expf(o0) - 1.f;
  o1 = o1 > 0.f ? o1 : __expf(o1) - 1.f;
  o2 = o2 > 0.f ? o2 : __expf(o2) - 1.f;
  o3 = o3 > 0.f ? o3 : __expf(o3) - 1.f;
  o4 = o4 > 0.f ? o4 : __expf(o4) - 1.f;
  o5 = o5 > 0.f ? o5 : __expf(o5) - 1.f;
  o6 = o6 > 0.f ? o6 : __expf(o6) - 1.f;
  o7 = o7 > 0.f ? o7 : __expf(o7) - 1.f;
  const float* wG = w2s + es*16 + fs;
  float gA = 0.f, gB = 0.f;
  gA += o0*wG[0];   gB += o0*wG[64];
  gA += o1*wG[128]; gB += o1*wG[192];
  gA += o2*wG[256]; gB += o2*wG[320];
  gA += o3*wG[384]; gB += o3*wG[448];
  gA += o4*wG[512]; gB += o4*wG[576];
  gA += o5*wG[640]; gB += o5*wG[704];
  gA += o6*wG[768]; gB += o6*wG[832];
  gA += o7*wG[896]; gB += o7*wG[960];
  #define RED4(X) { X += __shfl_xor(X,1); X += __shfl_xor(X,2); \
                    X += __shfl_xor(X,4); X += __shfl_xor(X,8); }
  RED4(gA) RED4(gB)
  #undef RED4
  float pal = gA*as2[es*2] + gB*as2[es*2+1];
  float par = gA*ad2[es*2] + gB*ad2[es*2+1];
  RED2(pal) RED2(par)
  #undef RED2
  if (fs == 0){
    *(__half2*)&h2[((size_t)node<<3) + es*2] = __floats2half2_rn(gA, gB);
  }
  if (lane == 0){
    al2[node] = pal;
    ar2[node] = par;
  }
}

// ---- layer-2 GAT, edge-parallel: lane = one CSR edge; segmented wave scan ----
__global__ __launch_bounds__(256) void k_gat2e(const int* __restrict__ csr_src,
    const int* __restrict__ csr_dst, const float* __restrict__ al,
    const float* __restrict__ ar, const unsigned* __restrict__ almax,
    const __half* __restrict__ h2, float* __restrict__ nacc,
    float* __restrict__ nden, int Etot){
  int e = blockIdx.x*256 + threadIdx.x;
  int lane = threadIdx.x & 63;
  bool ok = e < Etot;
  int s = ok ? csr_src[e] : 0;
  int d = ok ? csr_dst[e] : -1;
  float w = 0.f;
  if (ok){
    float ardv = ar[d];
    float v = al[s] + ardv; v = v > 0.f ? v : SLOPE*v;
    float ub = fdec(almax[0]) + ardv; ub = ub > 0.f ? ub : SLOPE*ub;
    w = __expf(v - ub);
  }
  float2 h01 = {0,0}, h23 = {0,0}, h45 = {0,0}, h67 = {0,0};
  if (ok){
    uint4 hv = *(const uint4*)&h2[((size_t)s<<3)];
    h01 = h2f2(hv.x); h23 = h2f2(hv.y); h45 = h2f2(hv.z); h67 = h2f2(hv.w);
  }
  float a0 = w*h01.x, a1 = w*h01.y, a2 = w*h23.x, a3 = w*h23.y;
  float a4 = w*h45.x, a5 = w*h45.y, a6 = w*h67.x, a7 = w*h67.y;
  float den = w;
  #pragma unroll
  for (int off = 1; off < 64; off <<= 1){
    int du = __shfl_up(d, off);
    bool add = (lane >= off) && (du == d);
    float t;
    t = __shfl_up(a0, off); if (add) a0 += t;
    t = __shfl_up(a1, off); if (add) a1 += t;
    t = __shfl_up(a2, off); if (add) a2 += t;
    t = __shfl_up(a3, off); if (add) a3 += t;
    t = __shfl_up(a4, off); if (add) a4 += t;
    t = __shfl_up(a5, off); if (add) a5 += t;
    t = __shfl_up(a6, off); if (add) a6 += t;
    t = __shfl_up(a7, off); if (add) a7 += t;
    t = __shfl_up(den, off); if (add) den += t;
  }
  int dn = __shfl_down(d, 1);
  bool tail = (lane == 63) || (dn != d);
  if (tail && d >= 0){
    float* np = nacc + ((size_t)d<<3);
    atomicAdd(np+0, a0); atomicAdd(np+1, a1);
    atomicAdd(np+2, a2); atomicAdd(np+3, a3);
    atomicAdd(np+4, a4); atomicAdd(np+5, a5);
    atomicAdd(np+6, a6); atomicAdd(np+7, a7);
    atomicAdd(&nden[d], den);
  }
}

// ---- finalize layer 2 + pool scatter ----
__global__ __launch_bounds__(256) void k_fin2(const float* __restrict__ nacc,
    const float* __restrict__ nden, const float* __restrict__ b2,
    const int* __restrict__ batch, float* __restrict__ pooled,
    float* __restrict__ cnt, int n){
  int t = blockIdx.x*256 + threadIdx.x;
  int node = t >> 3, j = t & 7;
  if (node >= n) return;
  float o = nacc[t] / (nden[node] + 1e-16f) + b2[j];
  int g = batch[node];
  atomicAdd(&pooled[g*C2N + j], o);
  if (j == 0) atomicAdd(&cnt[g], 1.f);
}

// ---- mean + log_softmax ----
__global__ __launch_bounds__(256) void k_final(const float* __restrict__ pooled,
    const float* __restrict__ cnt, float* __restrict__ out, int G){
  int g = blockIdx.x*blockDim.x + threadIdx.x;
  if (g >= G) return;
  float c = cnt[g]; c = c > 1.f ? c : 1.f;
  float p[8]; float mx = -1e30f;
  #pragma unroll
  for (int j = 0; j < 8; ++j){ p[j] = pooled[g*8+j] / c; mx = fmaxf(mx, p[j]); }
  float s = 0.f;
  #pragma unroll
  for (int j = 0; j < 8; ++j) s += expf(p[j]-mx);
  float lse = mx + logf(s);
  #pragma unroll
  for (int j = 0; j < 8; ++j) out[g*8+j] = p[j] - lse;
}

extern "C" void kernel_launch(void* const* d_in, const int* in_sizes, int n_in,
                              void* d_out, int out_size, void* d_ws, size_t ws_size,
                              hipStream_t stream){
  const float* x    = (const float*)d_in[0];
  const float* gam  = (const float*)d_in[1];
  const float* bet  = (const float*)d_in[2];
  const float* W1   = (const float*)d_in[3];
  const float* as1  = (const float*)d_in[4];
  const float* ad1  = (const float*)d_in[5];
  const float* b1   = (const float*)d_in[6];
  const float* W2   = (const float*)d_in[7];
  const float* as2  = (const float*)d_in[8];
  const float* ad2  = (const float*)d_in[9];
  const float* b2   = (const float*)d_in[10];
  const int*   ei   = (const int*)d_in[11];
  const int*   batch= (const int*)d_in[12];

  int N = in_sizes[0] / F1;
  int E = in_sizes[11] / 2;
  int G = out_size / C2N;
  int Etot = E + N;
  int nb = (N + 1023) / 1024;
  int NB = (N + (1<<BSH) - 1) >> BSH;
  int nbG = (N + 15) / 16;
  int nbS = (Etot + SB - 1) / SB;

  char* base = (char*)d_ws;
  auto alloc = [&](size_t bytes)->char*{
    char* p = base; base += (bytes + 15) & ~15ull; return p;
  };

  // ---- region A: zeroed every launch ----
  char* A0 = base;
  float*    sum     = (float*)alloc(128*4);
  float*    sumsq   = (float*)alloc(128*4);
  int*      deg     = (int*)alloc((size_t)N*4);
  float*    pooled  = (float*)alloc((size_t)G*C2N*4);
  float*    cnt     = (float*)alloc((size_t)G*4);
  unsigned* almax1u = (unsigned*)alloc(16);
  unsigned* almax2u = (unsigned*)alloc(16);
  float*    nacc    = (float*)alloc((size_t)N*C2N*4);
  float*    nden    = (float*)alloc((size_t)N*4);
  int*      bcur    = (int*)alloc((size_t)NB*64);   // relative cursors
  size_t Abytes = (size_t)(base - A0);
  // ---- rest ----
  int*     csr_src = (int*)alloc((size_t)Etot*4);
  int*     csr_dst = (int*)alloc((size_t)Etot*4);
  int2*    tmp     = (int2*)alloc((size_t)Etot*8);
  float*   ab      = (float*)alloc(256*4);
  int*     rowptr  = (int*)alloc(((size_t)N+4)*4);
  int*     cursor  = (int*)alloc((size_t)N*4);
  int*     bsum    = (int*)alloc((size_t)nb*4);
  unsigned char* h1 = (unsigned char*)alloc((size_t)N*F1);
  float*   al1     = (float*)alloc((size_t)N*4*4);
  float*   ar1     = (float*)alloc((size_t)N*4*4);
  __half*  h2      = (__half*)alloc((size_t)N*C2N*2);
  float*   al2     = (float*)alloc((size_t)N*4);
  float*   ar2     = (float*)alloc((size_t)N*4);

  hipMemsetAsync(A0, 0, Abytes, stream);

  k_bn_deg<<<256 + (E + 255)/256, 256, 0, stream>>>(x, sum, sumsq, N, ei, deg, E);
  k_scan_a_bn<<<nb + 1, 256, 0, stream>>>(deg, rowptr, bsum, N, sum, sumsq, gam, bet, ab);
  k_gemm1_scanc<<<nbG + nb, 256, 0, stream>>>(x, ab, W1, as1, ad1, h1, al1, ar1, N,
                                              rowptr, cursor, bsum, nb, nbG);
  k_sort_cmax<<<nbS + 128, 256, 0, stream>>>(ei, rowptr, bcur, tmp, E, Etot, NB,
                                             nbS, al1, almax1u, N*4);
  k_fill2<<<NB, 256, 0, stream>>>(rowptr, tmp, csr_src, csr_dst, cursor, N, NB);
  k_gat1<<<(N + 3)/4, 256, 0, stream>>>(rowptr, csr_src, al1, ar1, almax1u, h1, b1,
                                        W2, as2, ad2, h2, al2, ar2, N);
  k_colmax<<<64, 256, 0, stream>>>(al2, almax2u, N, 1);
  k_gat2e<<<(Etot + 255)/256, 256, 0, stream>>>(csr_src, csr_dst, al2, ar2, almax2u, h2, nacc, nden, Etot);
  k_fin2<<<((N*C2N) + 255)/256, 256, 0, stream>>>(nacc, nden, b2, batch, pooled, cnt, N);
  k_final<<<(G + 255)/256, 256, 0, stream>>>(pooled, cnt, (float*)d_out, G);
}

// Round 24
// 218.937 us; speedup vs baseline: 1.4983x; 1.1762x over previous
//
#include <hip/hip_runtime.h>
#include <hip/hip_fp16.h>
#include <math.h>

#define F1 128
#define C2N 8
#define SLOPE 0.2f
#define EPSBN 1e-5f
#define BCAP 4096
#define SB 4096
#define BSH 7      // 128 nodes per bucket
#define MAXB 1024

typedef float floatx2 __attribute__((ext_vector_type(2)));

__device__ __forceinline__ unsigned fenc(float f){
  unsigned u = __float_as_uint(f);
  return (u & 0x80000000u) ? ~u : (u | 0x80000000u);
}
__device__ __forceinline__ float fdec(unsigned u){
  return (u & 0x80000000u) ? __uint_as_float(u & 0x7FFFFFFFu) : __uint_as_float(~u);
}
__device__ __forceinline__ float2 h2f2(unsigned u){
  __half2 h = *(__half2*)&u;
  return __half22float2(h);
}

// ---- fused: BatchNorm stats (blocks 0..255) || dst-degree histogram (rest) ----
__global__ __launch_bounds__(256) void k_bn_deg(const float* __restrict__ x,
    float* __restrict__ sum, float* __restrict__ sumsq, int n,
    const int* __restrict__ ei, int* __restrict__ deg, int E){
  if ((int)blockIdx.x >= 256){
    int e = ((int)blockIdx.x - 256)*256 + threadIdx.x;
    if (e < E) atomicAdd(&deg[ei[E + e]], 1);
    return;
  }
  int t  = threadIdx.x;
  int c4 = (t & 31) * 4;
  int rg = t >> 5;
  float4 s = {0,0,0,0}, q = {0,0,0,0};
  for (int r = blockIdx.x*8 + rg; r < n; r += 2048){
    float4 v = *(const float4*)&x[(size_t)r*F1 + c4];
    s.x += v.x; s.y += v.y; s.z += v.z; s.w += v.w;
    q.x += v.x*v.x; q.y += v.y*v.y; q.z += v.z*v.z; q.w += v.w*v.w;
  }
  s.x += __shfl_xor(s.x, 32); s.y += __shfl_xor(s.y, 32);
  s.z += __shfl_xor(s.z, 32); s.w += __shfl_xor(s.w, 32);
  q.x += __shfl_xor(q.x, 32); q.y += __shfl_xor(q.y, 32);
  q.z += __shfl_xor(q.z, 32); q.w += __shfl_xor(q.w, 32);
  __shared__ float red[2][4][F1];
  int w = t >> 6;
  int l = t & 63;
  if (l < 32){
    *(float4*)&red[0][w][l*4] = s;
    *(float4*)&red[1][w][l*4] = q;
  }
  __syncthreads();
  if (t < 128){
    float a = red[0][0][t] + red[0][1][t] + red[0][2][t] + red[0][3][t];
    atomicAdd(&sum[t], a);
  } else {
    int f = t - 128;
    float a = red[1][0][f] + red[1][1][f] + red[1][2][f] + red[1][3][f];
    atomicAdd(&sumsq[f], a);
  }
}

// ---- fused: scan A (blocks 0..nb-1) || bn_final (last block) ----
__global__ __launch_bounds__(256) void k_scan_a_bn(const int* __restrict__ deg,
    int* __restrict__ rowptr, int* __restrict__ bsum, int n,
    const float* __restrict__ sum, const float* __restrict__ sumsq,
    const float* __restrict__ gamma, const float* __restrict__ beta,
    float* __restrict__ ab){
  int nbS = gridDim.x - 1;
  if ((int)blockIdx.x == nbS){
    int f = threadIdx.x;
    if (f < 128){
      float inv_n = 1.f / (float)n;
      float mean = sum[f] * inv_n;
      float var  = sumsq[f] * inv_n - mean*mean;
      float inv  = rsqrtf(var + EPSBN);
      float a = inv * gamma[f];
      ab[f]      = a;
      ab[F1 + f] = beta[f] - mean*a;
    }
    return;
  }
  int t = threadIdx.x;
  int base = blockIdx.x*1024 + t*4;
  int4 v = {0,0,0,0};
  if (base + 3 < n){
    v = *(const int4*)&deg[base];
    v.x += 1; v.y += 1; v.z += 1; v.w += 1;
  } else {
    if (base   < n) v.x = deg[base]   + 1;
    if (base+1 < n) v.y = deg[base+1] + 1;
    if (base+2 < n) v.z = deg[base+2] + 1;
    if (base+3 < n) v.w = deg[base+3] + 1;
  }
  int s = v.x + v.y + v.z + v.w;
  __shared__ int ls[256];
  ls[t] = s; __syncthreads();
  for (int off = 1; off < 256; off <<= 1){
    int u = (t >= off) ? ls[t-off] : 0;
    __syncthreads();
    ls[t] += u;
    __syncthreads();
  }
  int ex = ls[t] - s;
  if (t == 255) bsum[blockIdx.x] = ls[255];
  int4 w;
  w.x = ex;
  w.y = ex + v.x;
  w.z = w.y + v.y;
  w.w = w.z + v.z;
  if (base + 3 < n) *(int4*)&rowptr[base] = w;
  else {
    if (base   < n) rowptr[base]   = w.x;
    if (base+1 < n) rowptr[base+1] = w.y;
    if (base+2 < n) rowptr[base+2] = w.z;
    if (base+3 < n) rowptr[base+3] = w.w;
  }
}

// ---- fused: normalize + x@W1 + al1/ar1 (blocks < nbG) || scan C (rest) ----
__global__ __launch_bounds__(256) void k_gemm1_scanc(const float* __restrict__ x,
    const float* __restrict__ ab, const float* __restrict__ W1,
    const float* __restrict__ asrc, const float* __restrict__ adst,
    unsigned char* __restrict__ h1, float* __restrict__ al, float* __restrict__ ar,
    int n, int* __restrict__ rowptr, int* __restrict__ cursor,
    const int* __restrict__ bsum, int nb, int nbG){
  if ((int)blockIdx.x >= nbG){
    int sb = (int)blockIdx.x - nbG;      // scan-C block id, 0..nb-1
    int t = threadIdx.x;
    __shared__ int s_boff;
    if (t < 64){
      int val = 0;
      for (int i = t; i < sb; i += 64) val += bsum[i];
      #pragma unroll
      for (int m = 1; m < 64; m <<= 1) val += __shfl_xor(val, m);
      if (t == 0) s_boff = val;
    }
    __syncthreads();
    int boff = s_boff;
    if (t == 0 && sb == nb - 1)
      rowptr[n] = boff + bsum[sb];
    int base = sb*1024 + t*4;
    if (base + 3 < n){
      int4 v = *(int4*)&rowptr[base];
      v.x += boff; v.y += boff; v.z += boff; v.w += boff;
      *(int4*)&rowptr[base] = v;
      *(int4*)&cursor[base] = v;
    } else {
      for (int k = 0; k < 4; ++k)
        if (base + k < n){
          int v = rowptr[base+k] + boff;
          rowptr[base+k] = v; cursor[base+k] = v;
        }
    }
    return;
  }
  const int j    = threadIdx.x & 127;
  const int half = threadIdx.x >> 7;
  const int r0   = blockIdx.x * 16 + half*8;
  __shared__ float xs[16][F1];
  float A = ab[j], B = ab[F1 + j];
  int nr = n - r0; if (nr > 8) nr = 8; if (nr < 0) nr = 0;
  for (int rr = 0; rr < nr; ++rr)
    xs[half*8+rr][j] = x[(size_t)(r0+rr)*F1 + j] * A + B;
  __syncthreads();
  float acc[8] = {0,0,0,0,0,0,0,0};
  for (int k = 0; k < F1; ++k){
    float w = W1[k*F1 + j];
    #pragma unroll
    for (int rr = 0; rr < 8; ++rr) acc[rr] += xs[half*8+rr][k] * w;
  }
  float as = asrc[j], ad = adst[j];
  for (int rr = 0; rr < nr; ++rr){
    float hv = acc[rr];
    int pk = __builtin_amdgcn_cvt_pk_fp8_f32(hv, hv, 0, false);
    h1[(size_t)(r0+rr)*F1 + j] = (unsigned char)(pk & 0xFF);
    float vs = hv*as, vd = hv*ad;
    #pragma unroll
    for (int mk = 1; mk < 32; mk <<= 1){
      vs += __shfl_xor(vs, mk);
      vd += __shfl_xor(vd, mk);
    }
    if ((j & 31) == 0){
      al[(r0+rr)*4 + (j>>5)] = vs;
      ar[(r0+rr)*4 + (j>>5)] = vd;
    }
  }
}

// ---- global column max (standalone; layer 2) ----
__global__ __launch_bounds__(256) void k_colmax(const float* __restrict__ v,
    unsigned* __restrict__ out, int total, int H){
  int tid = blockIdx.x*256 + threadIdx.x;
  int stride = gridDim.x*256;
  float mx = -1e30f;
  for (int i = tid; i < total; i += stride)
    mx = fmaxf(mx, v[i]);
  for (int m = H; m < 64; m <<= 1)
    mx = fmaxf(mx, __shfl_xor(mx, m));
  int lane = threadIdx.x & 63;
  if (lane < H) atomicMax(&out[lane], fenc(mx));
}

// ---- fused: counting sort (blocks < nbS, relative bcur) || colmax1 (128) ----
__global__ __launch_bounds__(256) void k_sort_cmax(const int* __restrict__ ei,
    const int* __restrict__ rowptr, int* __restrict__ bcur,
    int2* __restrict__ tmp, int E, int Etot, int NB,
    int nbS, const float* __restrict__ al1, unsigned* __restrict__ almax1, int totalC){
  __shared__ int hist[MAXB];
  __shared__ int hbase[MAXB];
  __shared__ int2 stage[SB];
  if ((int)blockIdx.x >= nbS){
    int bid = (int)blockIdx.x - nbS;
    int tid = bid*256 + threadIdx.x;
    int stride = 128*256;
    float mx = -1e30f;
    for (int i = tid; i < totalC; i += stride)
      mx = fmaxf(mx, al1[i]);
    mx = fmaxf(mx, __shfl_xor(mx, 4));
    mx = fmaxf(mx, __shfl_xor(mx, 8));
    mx = fmaxf(mx, __shfl_xor(mx, 16));
    mx = fmaxf(mx, __shfl_xor(mx, 32));
    int lane = threadIdx.x & 63;
    if (lane < 4) atomicMax(&almax1[lane], fenc(mx));
    return;
  }
  int base_e = blockIdx.x * SB;
  int cnt = Etot - base_e; if (cnt > SB) cnt = SB;
  for (int i = threadIdx.x; i < NB; i += 256) hist[i] = 0;
  __syncthreads();
  for (int i = threadIdx.x; i < cnt; i += 256){
    int e = base_e + i;
    int s = (e < E) ? ei[e]     : (e - E);
    int d = (e < E) ? ei[E + e] : (e - E);
    stage[i] = make_int2(s, d);
    atomicAdd(&hist[d>>BSH], 1);
  }
  __syncthreads();
  for (int i = threadIdx.x; i < NB; i += 256){
    int c = hist[i];
    hbase[i] = c ? (rowptr[i<<BSH] + atomicAdd(&bcur[i*16], c)) : 0;
    hist[i] = 0;
  }
  __syncthreads();
  for (int i = threadIdx.x; i < cnt; i += 256){
    int2 sd = stage[i];
    int b = sd.y >> BSH;
    int off = atomicAdd(&hist[b], 1);
    tmp[hbase[b] + off] = sd;
  }
}

// ---- pass 2: per-bucket LDS scatter -> coalesced csr_src AND csr_dst ----
__global__ __launch_bounds__(256) void k_fill2(const int* __restrict__ rowptr,
    const int2* __restrict__ tmp, int* __restrict__ csr_src,
    int* __restrict__ csr_dst, int* __restrict__ cursor, int n, int NB){
  int b = blockIdx.x;
  int node0 = b << BSH;
  int node1 = node0 + (1<<BSH); if (node1 > n) node1 = n;
  int base = rowptr[node0];
  int endp = rowptr[node1];
  int size = endp - base;
  __shared__ int lcur[1<<BSH];
  __shared__ int2 lout[BCAP];
  if (size <= BCAP){
    if (threadIdx.x < (1<<BSH)){
      int nd = node0 + threadIdx.x;
      lcur[threadIdx.x] = (nd < node1) ? rowptr[nd] - base : 0;
    }
    __syncthreads();
    for (int i = threadIdx.x; i < size; i += 256){
      int2 sd = tmp[base + i];
      int rel = atomicAdd(&lcur[sd.y & ((1<<BSH)-1)], 1);
      lout[rel] = sd;
    }
    __syncthreads();
    for (int i = threadIdx.x; i < size; i += 256){
      int2 sd = lout[i];
      csr_src[base + i] = sd.x;
      csr_dst[base + i] = sd.y;
    }
  } else {
    for (int i = threadIdx.x; i < size; i += 256){
      int2 sd = tmp[base + i];
      int pos = atomicAdd(&cursor[sd.y], 1);
      csr_src[pos] = sd.x;
      csr_dst[pos] = sd.y;
    }
  }
}

// ---- layer-1 GAT + fused x1@W2: wave/node, 16 nodes per 1024-thr block ----
__global__ __launch_bounds__(1024) void k_gat1(const int* __restrict__ rowptr,
    const int* __restrict__ csr_src, const float* __restrict__ al,
    const float* __restrict__ ar, const unsigned* __restrict__ almax,
    const unsigned char* __restrict__ h1, const float* __restrict__ b1,
    const float* __restrict__ W2, const float* __restrict__ as2,
    const float* __restrict__ ad2, __half* __restrict__ h2,
    float* __restrict__ al2, float* __restrict__ ar2, int n){
  __shared__ float w2s[1024];
  {
    int a = threadIdx.x;
    int fs = a & 15;
    int es = (a >> 4) & 3;
    int r  = a >> 6;
    int kk = r >> 1;
    int jj = r & 1;
    w2s[a] = W2[(fs*8 + kk)*C2N + es*2 + jj];
  }
  __syncthreads();
  int node = blockIdx.x*16 + (threadIdx.x >> 6);
  if (node >= n) return;
  int lane = threadIdx.x & 63;
  int es = lane >> 4;
  int fs = lane & 15;
  int h  = fs >> 2;
  int f0 = fs << 3;
  int beg = rowptr[node], end = rowptr[node+1];
  float ard = ar[node*4 + h];
  float ub = fdec(almax[h]) + ard;
  ub = ub > 0.f ? ub : SLOPE*ub;
  float a0=0.f,a1=0.f,a2=0.f,a3=0.f,a4=0.f,a5=0.f,a6=0.f,a7=0.f,den=0.f;
  int c = beg;
  #define EDGE_GRP(SV, ALV, HV) { \
    float v_ = ALV + ard; v_ = v_ > 0.f ? v_ : SLOPE*v_; \
    float w_ = __expf(v_ - ub); \
    den += w_; \
    floatx2 r0_ = __builtin_amdgcn_cvt_pk_f32_fp8(HV.x, false); \
    floatx2 r1_ = __builtin_amdgcn_cvt_pk_f32_fp8(HV.x, true); \
    floatx2 r2_ = __builtin_amdgcn_cvt_pk_f32_fp8(HV.y, false); \
    floatx2 r3_ = __builtin_amdgcn_cvt_pk_f32_fp8(HV.y, true); \
    a0 += w_*r0_.x; a1 += w_*r0_.y; a2 += w_*r1_.x; a3 += w_*r1_.y; \
    a4 += w_*r2_.x; a5 += w_*r2_.y; a6 += w_*r3_.x; a7 += w_*r3_.y; }
  for (; c + 16 <= end; c += 16){
    int sA = csr_src[c + es];
    int sB = csr_src[c + 4 + es];
    int sC = csr_src[c + 8 + es];
    int sD = csr_src[c + 12 + es];
    float alA = al[sA*4 + h];
    float alB = al[sB*4 + h];
    float alC = al[sC*4 + h];
    float alD = al[sD*4 + h];
    uint2 hvA = *(const uint2*)&h1[((size_t)sA<<7) + f0];
    uint2 hvB = *(const uint2*)&h1[((size_t)sB<<7) + f0];
    uint2 hvC = *(const uint2*)&h1[((size_t)sC<<7) + f0];
    uint2 hvD = *(const uint2*)&h1[((size_t)sD<<7) + f0];
    EDGE_GRP(sA, alA, hvA)
    EDGE_GRP(sB, alB, hvB)
    EDGE_GRP(sC, alC, hvC)
    EDGE_GRP(sD, alD, hvD)
  }
  for (; c + 8 <= end; c += 8){
    int sA = csr_src[c + es];
    int sB = csr_src[c + 4 + es];
    float alA = al[sA*4 + h];
    float alB = al[sB*4 + h];
    uint2 hvA = *(const uint2*)&h1[((size_t)sA<<7) + f0];
    uint2 hvB = *(const uint2*)&h1[((size_t)sB<<7) + f0];
    EDGE_GRP(sA, alA, hvA)
    EDGE_GRP(sB, alB, hvB)
  }
  #undef EDGE_GRP
  for (; c < end; c += 4){
    int idx = c + es;
    bool ok = idx < end;
    int s = csr_src[ok ? idx : end-1];
    float alv = al[s*4 + h];
    float v = alv + ard; v = v > 0.f ? v : SLOPE*v;
    float wv = __expf(v - ub);
    wv = ok ? wv : 0.f;
    den += wv;
    uint2 hv = *(const uint2*)&h1[((size_t)s<<7) + f0];
    floatx2 p0 = __builtin_amdgcn_cvt_pk_f32_fp8(hv.x, false);
    floatx2 p1 = __builtin_amdgcn_cvt_pk_f32_fp8(hv.x, true);
    floatx2 p2 = __builtin_amdgcn_cvt_pk_f32_fp8(hv.y, false);
    floatx2 p3 = __builtin_amdgcn_cvt_pk_f32_fp8(hv.y, true);
    a0 += wv*p0.x; a1 += wv*p0.y; a2 += wv*p1.x; a3 += wv*p1.y;
    a4 += wv*p2.x; a5 += wv*p2.y; a6 += wv*p3.x; a7 += wv*p3.y;
  }
  #define RED2(X) { X += __shfl_xor(X,16); X += __shfl_xor(X,32); }
  RED2(a0) RED2(a1) RED2(a2) RED2(a3) RED2(a4) RED2(a5) RED2(a6) RED2(a7) RED2(den)
  float inv = 1.f / (den + 1e-16f);
  float4 bA = *(const float4*)&b1[f0];
  float4 bB = *(const float4*)&b1[f0+4];
  float o0 = a0*inv + bA.x, o1 = a1*inv + bA.y;
  float o2 = a2*inv + bA.z, o3 = a3*inv + bA.w;
  float o4 = a4*inv + bB.x, o5 = a5*inv + bB.y;
  float o6 = a6*inv + bB.z, o7 = a7*inv + bB.w;
  o0 = o0 > 0.f ? o0 : __expf(o0) - 1.f;
  o1 = o1 > 0.f ? o1 : __expf(o1) - 1.f;
  o2 = o2 > 0.f ? o2 : __expf(o2) - 1.f;
  o3 = o3 > 0.f ? o3 : __expf(o3) - 1.f;
  o4 = o4 > 0.f ? o4 : __expf(o4) - 1.f;
  o5 = o5 > 0.f ? o5 : __expf(o5) - 1.f;
  o6 = o6 > 0.f ? o6 : __expf(o6) - 1.f;
  o7 = o7 > 0.f ? o7 : __expf(o7) - 1.f;
  const float* wG = w2s + es*16 + fs;
  float gA = 0.f, gB = 0.f;
  gA += o0*wG[0];   gB += o0*wG[64];
  gA += o1*wG[128]; gB += o1*wG[192];
  gA += o2*wG[256]; gB += o2*wG[320];
  gA += o3*wG[384]; gB += o3*wG[448];
  gA += o4*wG[512]; gB += o4*wG[576];
  gA += o5*wG[640]; gB += o5*wG[704];
  gA += o6*wG[768]; gB += o6*wG[832];
  gA += o7*wG[896]; gB += o7*wG[960];
  #define RED4(X) { X += __shfl_xor(X,1); X += __shfl_xor(X,2); \
                    X += __shfl_xor(X,4); X += __shfl_xor(X,8); }
  RED4(gA) RED4(gB)
  #undef RED4
  float pal = gA*as2[es*2] + gB*as2[es*2+1];
  float par = gA*ad2[es*2] + gB*ad2[es*2+1];
  RED2(pal) RED2(par)
  #undef RED2
  if (fs == 0){
    *(__half2*)&h2[((size_t)node<<3) + es*2] = __floats2half2_rn(gA, gB);
  }
  if (lane == 0){
    al2[node] = pal;
    ar2[node] = par;
  }
}

// ---- layer-2 GAT, edge-parallel: lane = one CSR edge; segmented wave scan ----
__global__ __launch_bounds__(256) void k_gat2e(const int* __restrict__ csr_src,
    const int* __restrict__ csr_dst, const float* __restrict__ al,
    const float* __restrict__ ar, const unsigned* __restrict__ almax,
    const __half* __restrict__ h2, float* __restrict__ nacc,
    float* __restrict__ nden, int Etot){
  int e = blockIdx.x*256 + threadIdx.x;
  int lane = threadIdx.x & 63;
  bool ok = e < Etot;
  int s = ok ? csr_src[e] : 0;
  int d = ok ? csr_dst[e] : -1;
  float w = 0.f;
  if (ok){
    float ardv = ar[d];
    float v = al[s] + ardv; v = v > 0.f ? v : SLOPE*v;
    float ub = fdec(almax[0]) + ardv; ub = ub > 0.f ? ub : SLOPE*ub;
    w = __expf(v - ub);
  }
  float2 h01 = {0,0}, h23 = {0,0}, h45 = {0,0}, h67 = {0,0};
  if (ok){
    uint4 hv = *(const uint4*)&h2[((size_t)s<<3)];
    h01 = h2f2(hv.x); h23 = h2f2(hv.y); h45 = h2f2(hv.z); h67 = h2f2(hv.w);
  }
  float a0 = w*h01.x, a1 = w*h01.y, a2 = w*h23.x, a3 = w*h23.y;
  float a4 = w*h45.x, a5 = w*h45.y, a6 = w*h67.x, a7 = w*h67.y;
  float den = w;
  #pragma unroll
  for (int off = 1; off < 64; off <<= 1){
    int du = __shfl_up(d, off);
    bool add = (lane >= off) && (du == d);
    float t;
    t = __shfl_up(a0, off); if (add) a0 += t;
    t = __shfl_up(a1, off); if (add) a1 += t;
    t = __shfl_up(a2, off); if (add) a2 += t;
    t = __shfl_up(a3, off); if (add) a3 += t;
    t = __shfl_up(a4, off); if (add) a4 += t;
    t = __shfl_up(a5, off); if (add) a5 += t;
    t = __shfl_up(a6, off); if (add) a6 += t;
    t = __shfl_up(a7, off); if (add) a7 += t;
    t = __shfl_up(den, off); if (add) den += t;
  }
  int dn = __shfl_down(d, 1);
  bool tail = (lane == 63) || (dn != d);
  if (tail && d >= 0){
    float* np = nacc + ((size_t)d<<3);
    atomicAdd(np+0, a0); atomicAdd(np+1, a1);
    atomicAdd(np+2, a2); atomicAdd(np+3, a3);
    atomicAdd(np+4, a4); atomicAdd(np+5, a5);
    atomicAdd(np+6, a6); atomicAdd(np+7, a7);
    atomicAdd(&nden[d], den);
  }
}

// ---- fused finalize + pool + log_softmax: one block per graph ----
// batch is sorted, so graph g's nodes are a contiguous range found by
// binary search; block reduces its ~N/G nodes with no atomics/fences.
__global__ __launch_bounds__(256) void k_fin3(const float* __restrict__ nacc,
    const float* __restrict__ nden, const float* __restrict__ b2,
    const int* __restrict__ batch, float* __restrict__ out, int n, int G){
  int g = blockIdx.x;
  __shared__ int srange[2];
  if (threadIdx.x < 2){
    int tgt = g + threadIdx.x;
    int lo = 0, hi = n;
    while (lo < hi){
      int mid = (lo + hi) >> 1;
      if (batch[mid] < tgt) lo = mid + 1; else hi = mid;
    }
    srange[threadIdx.x] = lo;
  }
  __syncthreads();
  int lo = srange[0], hi = srange[1];
  int j = threadIdx.x & 7;
  float bj = b2[j];
  float acc = 0.f;
  for (int i = lo + (threadIdx.x >> 3); i < hi; i += 32)
    acc += nacc[(size_t)i*C2N + j] / (nden[i] + 1e-16f) + bj;
  // reduce across the 8 node-groups within each wave (lane bits 3..5)
  acc += __shfl_xor(acc, 8);
  acc += __shfl_xor(acc, 16);
  acc += __shfl_xor(acc, 32);
  __shared__ float wsum[4][8];
  int w = threadIdx.x >> 6;
  if ((threadIdx.x & 63) < 8) wsum[w][j] = acc;
  __syncthreads();
  __shared__ float pv[8];
  if (threadIdx.x < 8){
    float p = wsum[0][j] + wsum[1][j] + wsum[2][j] + wsum[3][j];
    float c = (float)(hi - lo); if (c < 1.f) c = 1.f;
    pv[j] = p / c;
  }
  __syncthreads();
  if (threadIdx.x < 8){
    float mx = pv[0];
    #pragma unroll
    for (int k = 1; k < 8; ++k) mx = fmaxf(mx, pv[k]);
    float s = 0.f;
    #pragma unroll
    for (int k = 0; k < 8; ++k) s += expf(pv[k] - mx);
    out[g*C2N + j] = pv[j] - (mx + logf(s));
  }
}

extern "C" void kernel_launch(void* const* d_in, const int* in_sizes, int n_in,
                              void* d_out, int out_size, void* d_ws, size_t ws_size,
                              hipStream_t stream){
  const float* x    = (const float*)d_in[0];
  const float* gam  = (const float*)d_in[1];
  const float* bet  = (const float*)d_in[2];
  const float* W1   = (const float*)d_in[3];
  const float* as1  = (const float*)d_in[4];
  const float* ad1  = (const float*)d_in[5];
  const float* b1   = (const float*)d_in[6];
  const float* W2   = (const float*)d_in[7];
  const float* as2  = (const float*)d_in[8];
  const float* ad2  = (const float*)d_in[9];
  const float* b2   = (const float*)d_in[10];
  const int*   ei   = (const int*)d_in[11];
  const int*   batch= (const int*)d_in[12];

  int N = in_sizes[0] / F1;
  int E = in_sizes[11] / 2;
  int G = out_size / C2N;
  int Etot = E + N;
  int nb = (N + 1023) / 1024;
  int NB = (N + (1<<BSH) - 1) >> BSH;
  int nbG = (N + 15) / 16;
  int nbS = (Etot + SB - 1) / SB;

  char* base = (char*)d_ws;
  auto alloc = [&](size_t bytes)->char*{
    char* p = base; base += (bytes + 15) & ~15ull; return p;
  };

  // ---- region A: zeroed every launch ----
  char* A0 = base;
  float*    sum     = (float*)alloc(128*4);
  float*    sumsq   = (float*)alloc(128*4);
  int*      deg     = (int*)alloc((size_t)N*4);
  unsigned* almax1u = (unsigned*)alloc(16);
  unsigned* almax2u = (unsigned*)alloc(16);
  float*    nacc    = (float*)alloc((size_t)N*C2N*4);
  float*    nden    = (float*)alloc((size_t)N*4);
  int*      bcur    = (int*)alloc((size_t)NB*64);   // relative cursors
  size_t Abytes = (size_t)(base - A0);
  // ---- rest ----
  int*     csr_src = (int*)alloc((size_t)Etot*4);
  int*     csr_dst = (int*)alloc((size_t)Etot*4);
  int2*    tmp     = (int2*)alloc((size_t)Etot*8);
  float*   ab      = (float*)alloc(256*4);
  int*     rowptr  = (int*)alloc(((size_t)N+4)*4);
  int*     cursor  = (int*)alloc((size_t)N*4);
  int*     bsum    = (int*)alloc((size_t)nb*4);
  unsigned char* h1 = (unsigned char*)alloc((size_t)N*F1);
  float*   al1     = (float*)alloc((size_t)N*4*4);
  float*   ar1     = (float*)alloc((size_t)N*4*4);
  __half*  h2      = (__half*)alloc((size_t)N*C2N*2);
  float*   al2     = (float*)alloc((size_t)N*4);
  float*   ar2     = (float*)alloc((size_t)N*4);

  hipMemsetAsync(A0, 0, Abytes, stream);

  k_bn_deg<<<256 + (E + 255)/256, 256, 0, stream>>>(x, sum, sumsq, N, ei, deg, E);
  k_scan_a_bn<<<nb + 1, 256, 0, stream>>>(deg, rowptr, bsum, N, sum, sumsq, gam, bet, ab);
  k_gemm1_scanc<<<nbG + nb, 256, 0, stream>>>(x, ab, W1, as1, ad1, h1, al1, ar1, N,
                                              rowptr, cursor, bsum, nb, nbG);
  k_sort_cmax<<<nbS + 128, 256, 0, stream>>>(ei, rowptr, bcur, tmp, E, Etot, NB,
                                             nbS, al1, almax1u, N*4);
  k_fill2<<<NB, 256, 0, stream>>>(rowptr, tmp, csr_src, csr_dst, cursor, N, NB);
  k_gat1<<<(N + 15)/16, 1024, 0, stream>>>(rowptr, csr_src, al1, ar1, almax1u, h1, b1,
                                           W2, as2, ad2, h2, al2, ar2, N);
  k_colmax<<<64, 256, 0, stream>>>(al2, almax2u, N, 1);
  k_gat2e<<<(Etot + 255)/256, 256, 0, stream>>>(csr_src, csr_dst, al2, ar2, almax2u, h2, nacc, nden, Etot);
  k_fin3<<<G, 256, 0, stream>>>(nacc, nden, b2, batch, (float*)d_out, N, G);
}

// Round 25
// 209.319 us; speedup vs baseline: 1.5671x; 1.0460x over previous
//
#include <hip/hip_runtime.h>
#include <hip/hip_fp16.h>
#include <math.h>

#define F1 128
#define C2N 8
#define SLOPE 0.2f
#define EPSBN 1e-5f
#define BCAP 4096
#define SB 4096
#define BSH 7      // 128 nodes per bucket
#define MAXB 1024

typedef float floatx2 __attribute__((ext_vector_type(2)));

__device__ __forceinline__ unsigned fenc(float f){
  unsigned u = __float_as_uint(f);
  return (u & 0x80000000u) ? ~u : (u | 0x80000000u);
}
__device__ __forceinline__ float fdec(unsigned u){
  return (u & 0x80000000u) ? __uint_as_float(u & 0x7FFFFFFFu) : __uint_as_float(~u);
}
__device__ __forceinline__ float2 h2f2(unsigned u){
  __half2 h = *(__half2*)&u;
  return __half22float2(h);
}

// ---- fused: BatchNorm stats (blocks 0..255) || dst-degree histogram (rest) ----
__global__ __launch_bounds__(256) void k_bn_deg(const float* __restrict__ x,
    float* __restrict__ sum, float* __restrict__ sumsq, int n,
    const int* __restrict__ ei, int* __restrict__ deg, int E){
  if ((int)blockIdx.x >= 256){
    int e = ((int)blockIdx.x - 256)*256 + threadIdx.x;
    if (e < E) atomicAdd(&deg[ei[E + e]], 1);
    return;
  }
  int t  = threadIdx.x;
  int c4 = (t & 31) * 4;
  int rg = t >> 5;
  float4 s = {0,0,0,0}, q = {0,0,0,0};
  for (int r = blockIdx.x*8 + rg; r < n; r += 2048){
    float4 v = *(const float4*)&x[(size_t)r*F1 + c4];
    s.x += v.x; s.y += v.y; s.z += v.z; s.w += v.w;
    q.x += v.x*v.x; q.y += v.y*v.y; q.z += v.z*v.z; q.w += v.w*v.w;
  }
  s.x += __shfl_xor(s.x, 32); s.y += __shfl_xor(s.y, 32);
  s.z += __shfl_xor(s.z, 32); s.w += __shfl_xor(s.w, 32);
  q.x += __shfl_xor(q.x, 32); q.y += __shfl_xor(q.y, 32);
  q.z += __shfl_xor(q.z, 32); q.w += __shfl_xor(q.w, 32);
  __shared__ float red[2][4][F1];
  int w = t >> 6;
  int l = t & 63;
  if (l < 32){
    *(float4*)&red[0][w][l*4] = s;
    *(float4*)&red[1][w][l*4] = q;
  }
  __syncthreads();
  if (t < 128){
    float a = red[0][0][t] + red[0][1][t] + red[0][2][t] + red[0][3][t];
    atomicAdd(&sum[t], a);
  } else {
    int f = t - 128;
    float a = red[1][0][f] + red[1][1][f] + red[1][2][f] + red[1][3][f];
    atomicAdd(&sumsq[f], a);
  }
}

// ---- fused: scan A (blocks 0..nb-1) || bn_final (last block) ----
__global__ __launch_bounds__(256) void k_scan_a_bn(const int* __restrict__ deg,
    int* __restrict__ rowptr, int* __restrict__ bsum, int n,
    const float* __restrict__ sum, const float* __restrict__ sumsq,
    const float* __restrict__ gamma, const float* __restrict__ beta,
    float* __restrict__ ab){
  int nbS = gridDim.x - 1;
  if ((int)blockIdx.x == nbS){
    int f = threadIdx.x;
    if (f < 128){
      float inv_n = 1.f / (float)n;
      float mean = sum[f] * inv_n;
      float var  = sumsq[f] * inv_n - mean*mean;
      float inv  = rsqrtf(var + EPSBN);
      float a = inv * gamma[f];
      ab[f]      = a;
      ab[F1 + f] = beta[f] - mean*a;
    }
    return;
  }
  int t = threadIdx.x;
  int base = blockIdx.x*1024 + t*4;
  int4 v = {0,0,0,0};
  if (base + 3 < n){
    v = *(const int4*)&deg[base];
    v.x += 1; v.y += 1; v.z += 1; v.w += 1;
  } else {
    if (base   < n) v.x = deg[base]   + 1;
    if (base+1 < n) v.y = deg[base+1] + 1;
    if (base+2 < n) v.z = deg[base+2] + 1;
    if (base+3 < n) v.w = deg[base+3] + 1;
  }
  int s = v.x + v.y + v.z + v.w;
  __shared__ int ls[256];
  ls[t] = s; __syncthreads();
  for (int off = 1; off < 256; off <<= 1){
    int u = (t >= off) ? ls[t-off] : 0;
    __syncthreads();
    ls[t] += u;
    __syncthreads();
  }
  int ex = ls[t] - s;
  if (t == 255) bsum[blockIdx.x] = ls[255];
  int4 w;
  w.x = ex;
  w.y = ex + v.x;
  w.z = w.y + v.y;
  w.w = w.z + v.z;
  if (base + 3 < n) *(int4*)&rowptr[base] = w;
  else {
    if (base   < n) rowptr[base]   = w.x;
    if (base+1 < n) rowptr[base+1] = w.y;
    if (base+2 < n) rowptr[base+2] = w.z;
    if (base+3 < n) rowptr[base+3] = w.w;
  }
}

// ---- fused: normalize + x@W1 + al1/ar1 (blocks < nbG) || scan C (rest) ----
__global__ __launch_bounds__(256) void k_gemm1_scanc(const float* __restrict__ x,
    const float* __restrict__ ab, const float* __restrict__ W1,
    const float* __restrict__ asrc, const float* __restrict__ adst,
    unsigned char* __restrict__ h1, float* __restrict__ al, float* __restrict__ ar,
    int n, int* __restrict__ rowptr, int* __restrict__ cursor,
    const int* __restrict__ bsum, int nb, int nbG){
  if ((int)blockIdx.x >= nbG){
    int sb = (int)blockIdx.x - nbG;      // scan-C block id, 0..nb-1
    int t = threadIdx.x;
    __shared__ int s_boff;
    if (t < 64){
      int val = 0;
      for (int i = t; i < sb; i += 64) val += bsum[i];
      #pragma unroll
      for (int m = 1; m < 64; m <<= 1) val += __shfl_xor(val, m);
      if (t == 0) s_boff = val;
    }
    __syncthreads();
    int boff = s_boff;
    if (t == 0 && sb == nb - 1)
      rowptr[n] = boff + bsum[sb];
    int base = sb*1024 + t*4;
    if (base + 3 < n){
      int4 v = *(int4*)&rowptr[base];
      v.x += boff; v.y += boff; v.z += boff; v.w += boff;
      *(int4*)&rowptr[base] = v;
      *(int4*)&cursor[base] = v;
    } else {
      for (int k = 0; k < 4; ++k)
        if (base + k < n){
          int v = rowptr[base+k] + boff;
          rowptr[base+k] = v; cursor[base+k] = v;
        }
    }
    return;
  }
  const int j    = threadIdx.x & 127;
  const int half = threadIdx.x >> 7;
  const int r0   = blockIdx.x * 16 + half*8;
  __shared__ float xs[16][F1];
  float A = ab[j], B = ab[F1 + j];
  int nr = n - r0; if (nr > 8) nr = 8; if (nr < 0) nr = 0;
  for (int rr = 0; rr < nr; ++rr)
    xs[half*8+rr][j] = x[(size_t)(r0+rr)*F1 + j] * A + B;
  __syncthreads();
  float acc[8] = {0,0,0,0,0,0,0,0};
  for (int k = 0; k < F1; ++k){
    float w = W1[k*F1 + j];
    #pragma unroll
    for (int rr = 0; rr < 8; ++rr) acc[rr] += xs[half*8+rr][k] * w;
  }
  float as = asrc[j], ad = adst[j];
  for (int rr = 0; rr < nr; ++rr){
    float hv = acc[rr];
    int pk = __builtin_amdgcn_cvt_pk_fp8_f32(hv, hv, 0, false);
    h1[(size_t)(r0+rr)*F1 + j] = (unsigned char)(pk & 0xFF);
    float vs = hv*as, vd = hv*ad;
    #pragma unroll
    for (int mk = 1; mk < 32; mk <<= 1){
      vs += __shfl_xor(vs, mk);
      vd += __shfl_xor(vd, mk);
    }
    if ((j & 31) == 0){
      al[(r0+rr)*4 + (j>>5)] = vs;
      ar[(r0+rr)*4 + (j>>5)] = vd;
    }
  }
}

// ---- global column max (standalone; layer 2) ----
__global__ __launch_bounds__(256) void k_colmax(const float* __restrict__ v,
    unsigned* __restrict__ out, int total, int H){
  int tid = blockIdx.x*256 + threadIdx.x;
  int stride = gridDim.x*256;
  float mx = -1e30f;
  for (int i = tid; i < total; i += stride)
    mx = fmaxf(mx, v[i]);
  for (int m = H; m < 64; m <<= 1)
    mx = fmaxf(mx, __shfl_xor(mx, m));
  int lane = threadIdx.x & 63;
  if (lane < H) atomicMax(&out[lane], fenc(mx));
}

// ---- fused: counting sort (blocks < nbS, relative bcur) || colmax1 (128) ----
__global__ __launch_bounds__(256) void k_sort_cmax(const int* __restrict__ ei,
    const int* __restrict__ rowptr, int* __restrict__ bcur,
    int2* __restrict__ tmp, int E, int Etot, int NB,
    int nbS, const float* __restrict__ al1, unsigned* __restrict__ almax1, int totalC){
  __shared__ int hist[MAXB];
  __shared__ int hbase[MAXB];
  __shared__ int2 stage[SB];
  if ((int)blockIdx.x >= nbS){
    int bid = (int)blockIdx.x - nbS;
    int tid = bid*256 + threadIdx.x;
    int stride = 128*256;
    float mx = -1e30f;
    for (int i = tid; i < totalC; i += stride)
      mx = fmaxf(mx, al1[i]);
    mx = fmaxf(mx, __shfl_xor(mx, 4));
    mx = fmaxf(mx, __shfl_xor(mx, 8));
    mx = fmaxf(mx, __shfl_xor(mx, 16));
    mx = fmaxf(mx, __shfl_xor(mx, 32));
    int lane = threadIdx.x & 63;
    if (lane < 4) atomicMax(&almax1[lane], fenc(mx));
    return;
  }
  int base_e = blockIdx.x * SB;
  int cnt = Etot - base_e; if (cnt > SB) cnt = SB;
  for (int i = threadIdx.x; i < NB; i += 256) hist[i] = 0;
  __syncthreads();
  for (int i = threadIdx.x; i < cnt; i += 256){
    int e = base_e + i;
    int s = (e < E) ? ei[e]     : (e - E);
    int d = (e < E) ? ei[E + e] : (e - E);
    stage[i] = make_int2(s, d);
    atomicAdd(&hist[d>>BSH], 1);
  }
  __syncthreads();
  for (int i = threadIdx.x; i < NB; i += 256){
    int c = hist[i];
    hbase[i] = c ? (rowptr[i<<BSH] + atomicAdd(&bcur[i*16], c)) : 0;
    hist[i] = 0;
  }
  __syncthreads();
  for (int i = threadIdx.x; i < cnt; i += 256){
    int2 sd = stage[i];
    int b = sd.y >> BSH;
    int off = atomicAdd(&hist[b], 1);
    tmp[hbase[b] + off] = sd;
  }
}

// ---- pass 2: per-bucket LDS scatter -> coalesced csr_src AND csr_dst ----
__global__ __launch_bounds__(256) void k_fill2(const int* __restrict__ rowptr,
    const int2* __restrict__ tmp, int* __restrict__ csr_src,
    int* __restrict__ csr_dst, int* __restrict__ cursor, int n, int NB){
  int b = blockIdx.x;
  int node0 = b << BSH;
  int node1 = node0 + (1<<BSH); if (node1 > n) node1 = n;
  int base = rowptr[node0];
  int endp = rowptr[node1];
  int size = endp - base;
  __shared__ int lcur[1<<BSH];
  __shared__ int2 lout[BCAP];
  if (size <= BCAP){
    if (threadIdx.x < (1<<BSH)){
      int nd = node0 + threadIdx.x;
      lcur[threadIdx.x] = (nd < node1) ? rowptr[nd] - base : 0;
    }
    __syncthreads();
    for (int i = threadIdx.x; i < size; i += 256){
      int2 sd = tmp[base + i];
      int rel = atomicAdd(&lcur[sd.y & ((1<<BSH)-1)], 1);
      lout[rel] = sd;
    }
    __syncthreads();
    for (int i = threadIdx.x; i < size; i += 256){
      int2 sd = lout[i];
      csr_src[base + i] = sd.x;
      csr_dst[base + i] = sd.y;
    }
  } else {
    for (int i = threadIdx.x; i < size; i += 256){
      int2 sd = tmp[base + i];
      int pos = atomicAdd(&cursor[sd.y], 1);
      csr_src[pos] = sd.x;
      csr_dst[pos] = sd.y;
    }
  }
}

// ---- layer-1 GAT + fused x1@W2: wave/node, 4 nodes per 256-thr block ----
__global__ __launch_bounds__(256) void k_gat1(const int* __restrict__ rowptr,
    const int* __restrict__ csr_src, const float* __restrict__ al,
    const float* __restrict__ ar, const unsigned* __restrict__ almax,
    const unsigned char* __restrict__ h1, const float* __restrict__ b1,
    const float* __restrict__ W2, const float* __restrict__ as2,
    const float* __restrict__ ad2, __half* __restrict__ h2,
    float* __restrict__ al2, float* __restrict__ ar2, int n){
  __shared__ float w2s[1024];
  for (int a = threadIdx.x; a < 1024; a += 256){
    int fs = a & 15;
    int es = (a >> 4) & 3;
    int r  = a >> 6;
    int kk = r >> 1;
    int jj = r & 1;
    w2s[a] = W2[(fs*8 + kk)*C2N + es*2 + jj];
  }
  __syncthreads();
  int node = blockIdx.x*4 + (threadIdx.x >> 6);
  if (node >= n) return;
  int lane = threadIdx.x & 63;
  int es = lane >> 4;
  int fs = lane & 15;
  int h  = fs >> 2;
  int f0 = fs << 3;
  int beg = rowptr[node], end = rowptr[node+1];
  float ard = ar[node*4 + h];
  float ub = fdec(almax[h]) + ard;
  ub = ub > 0.f ? ub : SLOPE*ub;
  float a0=0.f,a1=0.f,a2=0.f,a3=0.f,a4=0.f,a5=0.f,a6=0.f,a7=0.f,den=0.f;
  int c = beg;
  #define EDGE_GRP(SV, ALV, HV) { \
    float v_ = ALV + ard; v_ = v_ > 0.f ? v_ : SLOPE*v_; \
    float w_ = __expf(v_ - ub); \
    den += w_; \
    floatx2 r0_ = __builtin_amdgcn_cvt_pk_f32_fp8(HV.x, false); \
    floatx2 r1_ = __builtin_amdgcn_cvt_pk_f32_fp8(HV.x, true); \
    floatx2 r2_ = __builtin_amdgcn_cvt_pk_f32_fp8(HV.y, false); \
    floatx2 r3_ = __builtin_amdgcn_cvt_pk_f32_fp8(HV.y, true); \
    a0 += w_*r0_.x; a1 += w_*r0_.y; a2 += w_*r1_.x; a3 += w_*r1_.y; \
    a4 += w_*r2_.x; a5 += w_*r2_.y; a6 += w_*r3_.x; a7 += w_*r3_.y; }
  for (; c + 16 <= end; c += 16){
    int sA = csr_src[c + es];
    int sB = csr_src[c + 4 + es];
    int sC = csr_src[c + 8 + es];
    int sD = csr_src[c + 12 + es];
    float alA = al[sA*4 + h];
    float alB = al[sB*4 + h];
    float alC = al[sC*4 + h];
    float alD = al[sD*4 + h];
    uint2 hvA = *(const uint2*)&h1[((size_t)sA<<7) + f0];
    uint2 hvB = *(const uint2*)&h1[((size_t)sB<<7) + f0];
    uint2 hvC = *(const uint2*)&h1[((size_t)sC<<7) + f0];
    uint2 hvD = *(const uint2*)&h1[((size_t)sD<<7) + f0];
    EDGE_GRP(sA, alA, hvA)
    EDGE_GRP(sB, alB, hvB)
    EDGE_GRP(sC, alC, hvC)
    EDGE_GRP(sD, alD, hvD)
  }
  for (; c + 8 <= end; c += 8){
    int sA = csr_src[c + es];
    int sB = csr_src[c + 4 + es];
    float alA = al[sA*4 + h];
    float alB = al[sB*4 + h];
    uint2 hvA = *(const uint2*)&h1[((size_t)sA<<7) + f0];
    uint2 hvB = *(const uint2*)&h1[((size_t)sB<<7) + f0];
    EDGE_GRP(sA, alA, hvA)
    EDGE_GRP(sB, alB, hvB)
  }
  #undef EDGE_GRP
  for (; c < end; c += 4){
    int idx = c + es;
    bool ok = idx < end;
    int s = csr_src[ok ? idx : end-1];
    float alv = al[s*4 + h];
    float v = alv + ard; v = v > 0.f ? v : SLOPE*v;
    float wv = __expf(v - ub);
    wv = ok ? wv : 0.f;
    den += wv;
    uint2 hv = *(const uint2*)&h1[((size_t)s<<7) + f0];
    floatx2 p0 = __builtin_amdgcn_cvt_pk_f32_fp8(hv.x, false);
    floatx2 p1 = __builtin_amdgcn_cvt_pk_f32_fp8(hv.x, true);
    floatx2 p2 = __builtin_amdgcn_cvt_pk_f32_fp8(hv.y, false);
    floatx2 p3 = __builtin_amdgcn_cvt_pk_f32_fp8(hv.y, true);
    a0 += wv*p0.x; a1 += wv*p0.y; a2 += wv*p1.x; a3 += wv*p1.y;
    a4 += wv*p2.x; a5 += wv*p2.y; a6 += wv*p3.x; a7 += wv*p3.y;
  }
  #define RED2(X) { X += __shfl_xor(X,16); X += __shfl_xor(X,32); }
  RED2(a0) RED2(a1) RED2(a2) RED2(a3) RED2(a4) RED2(a5) RED2(a6) RED2(a7) RED2(den)
  float inv = 1.f / (den + 1e-16f);
  float4 bA = *(const float4*)&b1[f0];
  float4 bB = *(const float4*)&b1[f0+4];
  float o0 = a0*inv + bA.x, o1 = a1*inv + bA.y;
  float o2 = a2*inv + bA.z, o3 = a3*inv + bA.w;
  float o4 = a4*inv + bB.x, o5 = a5*inv + bB.y;
  float o6 = a6*inv + bB.z, o7 = a7*inv + bB.w;
  o0 = o0 > 0.f ? o0 : __expf(o0) - 1.f;
  o1 = o1 > 0.f ? o1 : __expf(o1) - 1.f;
  o2 = o2 > 0.f ? o2 : __expf(o2) - 1.f;
  o3 = o3 > 0.f ? o3 : __expf(o3) - 1.f;
  o4 = o4 > 0.f ? o4 : __expf(o4) - 1.f;
  o5 = o5 > 0.f ? o5 : __expf(o5) - 1.f;
  o6 = o6 > 0.f ? o6 : __expf(o6) - 1.f;
  o7 = o7 > 0.f ? o7 : __expf(o7) - 1.f;
  const float* wG = w2s + es*16 + fs;
  float gA = 0.f, gB = 0.f;
  gA += o0*wG[0];   gB += o0*wG[64];
  gA += o1*wG[128]; gB += o1*wG[192];
  gA += o2*wG[256]; gB += o2*wG[320];
  gA += o3*wG[384]; gB += o3*wG[448];
  gA += o4*wG[512]; gB += o4*wG[576];
  gA += o5*wG[640]; gB += o5*wG[704];
  gA += o6*wG[768]; gB += o6*wG[832];
  gA += o7*wG[896]; gB += o7*wG[960];
  #define RED4(X) { X += __shfl_xor(X,1); X += __shfl_xor(X,2); \
                    X += __shfl_xor(X,4); X += __shfl_xor(X,8); }
  RED4(gA) RED4(gB)
  #undef RED4
  float pal = gA*as2[es*2] + gB*as2[es*2+1];
  float par = gA*ad2[es*2] + gB*ad2[es*2+1];
  RED2(pal) RED2(par)
  #undef RED2
  if (fs == 0){
    *(__half2*)&h2[((size_t)node<<3) + es*2] = __floats2half2_rn(gA, gB);
  }
  if (lane == 0){
    al2[node] = pal;
    ar2[node] = par;
  }
}

// ---- layer-2 GAT, edge-parallel: lane = one CSR edge; segmented wave scan ----
__global__ __launch_bounds__(256) void k_gat2e(const int* __restrict__ csr_src,
    const int* __restrict__ csr_dst, const float* __restrict__ al,
    const float* __restrict__ ar, const unsigned* __restrict__ almax,
    const __half* __restrict__ h2, float* __restrict__ nacc,
    float* __restrict__ nden, int Etot){
  int e = blockIdx.x*256 + threadIdx.x;
  int lane = threadIdx.x & 63;
  bool ok = e < Etot;
  int s = ok ? csr_src[e] : 0;
  int d = ok ? csr_dst[e] : -1;
  float w = 0.f;
  if (ok){
    float ardv = ar[d];
    float v = al[s] + ardv; v = v > 0.f ? v : SLOPE*v;
    float ub = fdec(almax[0]) + ardv; ub = ub > 0.f ? ub : SLOPE*ub;
    w = __expf(v - ub);
  }
  float2 h01 = {0,0}, h23 = {0,0}, h45 = {0,0}, h67 = {0,0};
  if (ok){
    uint4 hv = *(const uint4*)&h2[((size_t)s<<3)];
    h01 = h2f2(hv.x); h23 = h2f2(hv.y); h45 = h2f2(hv.z); h67 = h2f2(hv.w);
  }
  float a0 = w*h01.x, a1 = w*h01.y, a2 = w*h23.x, a3 = w*h23.y;
  float a4 = w*h45.x, a5 = w*h45.y, a6 = w*h67.x, a7 = w*h67.y;
  float den = w;
  #pragma unroll
  for (int off = 1; off < 64; off <<= 1){
    int du = __shfl_up(d, off);
    bool add = (lane >= off) && (du == d);
    float t;
    t = __shfl_up(a0, off); if (add) a0 += t;
    t = __shfl_up(a1, off); if (add) a1 += t;
    t = __shfl_up(a2, off); if (add) a2 += t;
    t = __shfl_up(a3, off); if (add) a3 += t;
    t = __shfl_up(a4, off); if (add) a4 += t;
    t = __shfl_up(a5, off); if (add) a5 += t;
    t = __shfl_up(a6, off); if (add) a6 += t;
    t = __shfl_up(a7, off); if (add) a7 += t;
    t = __shfl_up(den, off); if (add) den += t;
  }
  int dn = __shfl_down(d, 1);
  bool tail = (lane == 63) || (dn != d);
  if (tail && d >= 0){
    float* np = nacc + ((size_t)d<<3);
    atomicAdd(np+0, a0); atomicAdd(np+1, a1);
    atomicAdd(np+2, a2); atomicAdd(np+3, a3);
    atomicAdd(np+4, a4); atomicAdd(np+5, a5);
    atomicAdd(np+6, a6); atomicAdd(np+7, a7);
    atomicAdd(&nden[d], den);
  }
}

// ---- fused finalize + pool + log_softmax: one block per graph ----
__global__ __launch_bounds__(256) void k_fin3(const float* __restrict__ nacc,
    const float* __restrict__ nden, const float* __restrict__ b2,
    const int* __restrict__ batch, float* __restrict__ out, int n, int G){
  int g = blockIdx.x;
  __shared__ int srange[2];
  if (threadIdx.x < 2){
    int tgt = g + threadIdx.x;
    int lo = 0, hi = n;
    while (lo < hi){
      int mid = (lo + hi) >> 1;
      if (batch[mid] < tgt) lo = mid + 1; else hi = mid;
    }
    srange[threadIdx.x] = lo;
  }
  __syncthreads();
  int lo = srange[0], hi = srange[1];
  int j = threadIdx.x & 7;
  float bj = b2[j];
  float acc = 0.f;
  for (int i = lo + (threadIdx.x >> 3); i < hi; i += 32)
    acc += nacc[(size_t)i*C2N + j] / (nden[i] + 1e-16f) + bj;
  acc += __shfl_xor(acc, 8);
  acc += __shfl_xor(acc, 16);
  acc += __shfl_xor(acc, 32);
  __shared__ float wsum[4][8];
  int w = threadIdx.x >> 6;
  if ((threadIdx.x & 63) < 8) wsum[w][j] = acc;
  __syncthreads();
  __shared__ float pv[8];
  if (threadIdx.x < 8){
    float p = wsum[0][j] + wsum[1][j] + wsum[2][j] + wsum[3][j];
    float c = (float)(hi - lo); if (c < 1.f) c = 1.f;
    pv[j] = p / c;
  }
  __syncthreads();
  if (threadIdx.x < 8){
    float mx = pv[0];
    #pragma unroll
    for (int k = 1; k < 8; ++k) mx = fmaxf(mx, pv[k]);
    float s = 0.f;
    #pragma unroll
    for (int k = 0; k < 8; ++k) s += expf(pv[k] - mx);
    out[g*C2N + j] = pv[j] - (mx + logf(s));
  }
}

extern "C" void kernel_launch(void* const* d_in, const int* in_sizes, int n_in,
                              void* d_out, int out_size, void* d_ws, size_t ws_size,
                              hipStream_t stream){
  const float* x    = (const float*)d_in[0];
  const float* gam  = (const float*)d_in[1];
  const float* bet  = (const float*)d_in[2];
  const float* W1   = (const float*)d_in[3];
  const float* as1  = (const float*)d_in[4];
  const float* ad1  = (const float*)d_in[5];
  const float* b1   = (const float*)d_in[6];
  const float* W2   = (const float*)d_in[7];
  const float* as2  = (const float*)d_in[8];
  const float* ad2  = (const float*)d_in[9];
  const float* b2   = (const float*)d_in[10];
  const int*   ei   = (const int*)d_in[11];
  const int*   batch= (const int*)d_in[12];

  int N = in_sizes[0] / F1;
  int E = in_sizes[11] / 2;
  int G = out_size / C2N;
  int Etot = E + N;
  int nb = (N + 1023) / 1024;
  int NB = (N + (1<<BSH) - 1) >> BSH;
  int nbG = (N + 15) / 16;
  int nbS = (Etot + SB - 1) / SB;

  char* base = (char*)d_ws;
  auto alloc = [&](size_t bytes)->char*{
    char* p = base; base += (bytes + 15) & ~15ull; return p;
  };

  // ---- region A: zeroed every launch ----
  char* A0 = base;
  float*    sum     = (float*)alloc(128*4);
  float*    sumsq   = (float*)alloc(128*4);
  int*      deg     = (int*)alloc((size_t)N*4);
  unsigned* almax1u = (unsigned*)alloc(16);
  unsigned* almax2u = (unsigned*)alloc(16);
  float*    nacc    = (float*)alloc((size_t)N*C2N*4);
  float*    nden    = (float*)alloc((size_t)N*4);
  int*      bcur    = (int*)alloc((size_t)NB*64);   // relative cursors
  size_t Abytes = (size_t)(base - A0);
  // ---- rest ----
  int*     csr_src = (int*)alloc((size_t)Etot*4);
  int*     csr_dst = (int*)alloc((size_t)Etot*4);
  int2*    tmp     = (int2*)alloc((size_t)Etot*8);
  float*   ab      = (float*)alloc(256*4);
  int*     rowptr  = (int*)alloc(((size_t)N+4)*4);
  int*     cursor  = (int*)alloc((size_t)N*4);
  int*     bsum    = (int*)alloc((size_t)nb*4);
  unsigned char* h1 = (unsigned char*)alloc((size_t)N*F1);
  float*   al1     = (float*)alloc((size_t)N*4*4);
  float*   ar1     = (float*)alloc((size_t)N*4*4);
  __half*  h2      = (__half*)alloc((size_t)N*C2N*2);
  float*   al2     = (float*)alloc((size_t)N*4);
  float*   ar2     = (float*)alloc((size_t)N*4);

  hipMemsetAsync(A0, 0, Abytes, stream);

  k_bn_deg<<<256 + (E + 255)/256, 256, 0, stream>>>(x, sum, sumsq, N, ei, deg, E);
  k_scan_a_bn<<<nb + 1, 256, 0, stream>>>(deg, rowptr, bsum, N, sum, sumsq, gam, bet, ab);
  k_gemm1_scanc<<<nbG + nb, 256, 0, stream>>>(x, ab, W1, as1, ad1, h1, al1, ar1, N,
                                              rowptr, cursor, bsum, nb, nbG);
  k_sort_cmax<<<nbS + 128, 256, 0, stream>>>(ei, rowptr, bcur, tmp, E, Etot, NB,
                                             nbS, al1, almax1u, N*4);
  k_fill2<<<NB, 256, 0, stream>>>(rowptr, tmp, csr_src, csr_dst, cursor, N, NB);
  k_gat1<<<(N + 3)/4, 256, 0, stream>>>(rowptr, csr_src, al1, ar1, almax1u, h1, b1,
                                        W2, as2, ad2, h2, al2, ar2, N);
  k_colmax<<<64, 256, 0, stream>>>(al2, almax2u, N, 1);
  k_gat2e<<<(Etot + 255)/256, 256, 0, stream>>>(csr_src, csr_dst, al2, ar2, almax2u, h2, nacc, nden, Etot);
  k_fin3<<<G, 256, 0, stream>>>(nacc, nden, b2, batch, (float*)d_out, N, G);
}